// Round 14
// baseline (170.183 us; speedup 1.0000x reference)
//
#include <hip/hip_runtime.h>
#include <hip/hip_bf16.h>
#include <math.h>

#define H 128
#define R 32
#define NATOMS 2048
#define NEDGES 32768
#define NH (NATOMS * H)          // 262144 (n,h) pairs
#define NP 1152                  // 9*H: node-plane row stride (interleaved [n][9][H])
#define NPY 1536                 // 64 pairs * 24: Y pair-record stride per atom
#define CUTOFF_F 4.5f
#define PI_OVER_CUTOFF 0.6981317007977318f

typedef __bf16 bf16x8 __attribute__((ext_vector_type(8)));
typedef float f32x4 __attribute__((ext_vector_type(4)));
typedef short short8 __attribute__((ext_vector_type(8)));
typedef unsigned short u16x4 __attribute__((ext_vector_type(4)));

// lgkm-only barrier: LDS visible, global loads stay in flight across it.
#define BAR_LGKM() do { \
    asm volatile("s_waitcnt lgkmcnt(0)" ::: "memory"); \
    __builtin_amdgcn_s_barrier(); \
    asm volatile("" ::: "memory"); \
} while (0)

// ---------------------------------------------------------------------------
__device__ __forceinline__ float silu_f(float x) {
    return x / (1.f + __expf(-x));
}
__device__ __forceinline__ float b2f(unsigned short u) {
    return __uint_as_float(((unsigned)u) << 16);
}
__device__ __forceinline__ float b2f_lo(unsigned u) {
    return __uint_as_float(u << 16);
}
__device__ __forceinline__ float b2f_hi(unsigned u) {
    return __uint_as_float(u & 0xffff0000u);
}
__device__ __forceinline__ unsigned short f2b(float f) {
    __hip_bfloat16 h = __float2bfloat16(f);
    return __builtin_bit_cast(unsigned short, h);
}

// Build full 3x3 from decomposition [i0, a01, a02, a12, s00, s01, s02, s11, s12]
__device__ __forceinline__ void build_full(const float d[9], float m[9]) {
    float i0 = d[0], a01 = d[1], a02 = d[2], a12 = d[3];
    float s00 = d[4], s01 = d[5], s02 = d[6], s11 = d[7], s12 = d[8];
    float s22 = -(s00 + s11);
    m[0] = i0 + s00;  m[1] = a01 + s01;  m[2] = a02 + s02;
    m[3] = s01 - a01; m[4] = i0 + s11;   m[5] = a12 + s12;
    m[6] = s02 - a02; m[7] = s12 - a12;  m[8] = i0 + s22;
}

// ---------------------------------------------------------------------------
// One-shot cast of all fp32 params to bf16 + CSR cnt zeroing + node prep
#define C0 (NEDGES * R)          // edge_attr
#define C1 (2 * H * R)           // Ws1
#define C2 (2 * 2 * H * H)       // Ws2
#define C3 (2 * 3 * H * 2 * H)   // Ws3
#define C4 (2 * 6 * H * H)       // Wt
#define C5 2048                  // cnt zero
#define CAST_TOTAL (C0 + C1 + C2 + C3 + C4 + C5 + NH)
__global__ __launch_bounds__(256) void k_cast_all(
        const float* __restrict__ ea, const float* __restrict__ w1,
        const float* __restrict__ w2, const float* __restrict__ w3,
        const float* __restrict__ wt,
        __hip_bfloat16* __restrict__ oea, __hip_bfloat16* __restrict__ ow1,
        __hip_bfloat16* __restrict__ ow2, __hip_bfloat16* __restrict__ ow3,
        __hip_bfloat16* __restrict__ owt, int* __restrict__ cnt,
        const float* __restrict__ X, float* __restrict__ Xn,
        __hip_bfloat16* __restrict__ Db) {
    int i = blockIdx.x * 256 + threadIdx.x;
    if (i < C0) { oea[i] = __float2bfloat16(ea[i]); return; }
    i -= C0;
    if (i < C1) { ow1[i] = __float2bfloat16(w1[i]); return; }
    i -= C1;
    if (i < C2) { ow2[i] = __float2bfloat16(w2[i]); return; }
    i -= C2;
    if (i < C3) { ow3[i] = __float2bfloat16(w3[i]); return; }
    i -= C3;
    if (i < C4) { owt[i] = __float2bfloat16(wt[i]); return; }
    i -= C4;
    if (i < C5) { cnt[i] = 0; return; }
    i -= C5;
    if (i < NH) {
        const float* x = X + (size_t)i * 9;
        float v[9];
        float ss = 0.f;
#pragma unroll
        for (int j = 0; j < 9; j++) { v[j] = x[j]; ss += v[j] * v[j]; }
        float inv = 1.f / (ss + 1.f);
#pragma unroll
        for (int j = 0; j < 9; j++) { v[j] *= inv; Xn[(size_t)i * 9 + j] = v[j]; }
        float i0 = (v[0] + v[4] + v[8]) * (1.f / 3.f);
        unsigned short* D = (unsigned short*)Db + (size_t)(i >> 7) * NP + (i & 127);
        D[0 * H] = f2b(i0);
        D[1 * H] = f2b(0.5f * (v[1] - v[3]));
        D[2 * H] = f2b(0.5f * (v[2] - v[6]));
        D[3 * H] = f2b(0.5f * (v[5] - v[7]));
        D[4 * H] = f2b(v[0] - i0);
        D[5 * H] = f2b(0.5f * (v[1] + v[3]));
        D[6 * H] = f2b(0.5f * (v[2] + v[6]));
        D[7 * H] = f2b(v[4] - i0);
        D[8 * H] = f2b(0.5f * (v[5] + v[7]));
    }
}

// ---------------------------------------------------------------------------
// bf16 MFMA 128x64 tile-GEMM core for the channel mix (K=128), strided A.
struct TGm {
    static constexpr int BKm = 64;
    static constexpr int RB  = 128;        // row bytes per K-step
    static constexpr int SWZ = 7;
    static constexpr int NIT = 2;
    static constexpr int ABYTES = 128 * RB;
    static constexpr int BBYTES = 64 * RB;
    static constexpr int AISS = ABYTES / 4096;
    static constexpr int BISS = BBYTES / 4096;
    static constexpr int LDSB = ABYTES + BBYTES;
};

__device__ __forceinline__ void tile_gemm_mix(
        const __hip_bfloat16* __restrict__ A, int strideA,
        const __hip_bfloat16* __restrict__ W,
        int m0, int n0, char* lds, f32x4 acc[4][2]) {
    using T = TGm;
    const int t = threadIdx.x;
    const int lane = t & 63;
    const int w = t >> 6;

    auto stage = [&](int b, int it) {
        const int k0 = it * T::BKm;
        char* As = lds + b * T::LDSB;
        char* Bs = As + T::ABYTES;
#pragma unroll
        for (int i = 0; i < T::AISS; i++) {
            int base = (w * T::AISS + i) * 1024;
            int lin = base + lane * 16;
            int row = lin / T::RB;
            int slot = (lin % T::RB) >> 4;
            int sl = slot ^ (row & T::SWZ);
            const char* src = (const char*)(A + (size_t)(m0 + row) * strideA + k0) + sl * 16;
            __builtin_amdgcn_global_load_lds(
                (const __attribute__((address_space(1))) void*)src,
                (__attribute__((address_space(3))) void*)(As + base), 16, 0, 0);
        }
#pragma unroll
        for (int i = 0; i < T::BISS; i++) {
            int base = (w * T::BISS + i) * 1024;
            int lin = base + lane * 16;
            int row = lin / T::RB;
            int slot = (lin % T::RB) >> 4;
            int sl = slot ^ (row & T::SWZ);
            const char* src = (const char*)(W + (size_t)(n0 + row) * H + k0) + sl * 16;
            __builtin_amdgcn_global_load_lds(
                (const __attribute__((address_space(1))) void*)src,
                (__attribute__((address_space(3))) void*)(Bs + base), 16, 0, 0);
        }
    };

    auto compute = [&](int b) {
        const char* As = lds + b * T::LDSB;
        const char* Bs = As + T::ABYTES;
        const int wm = (w & 1) * 64;
        const int wn = (w >> 1) * 32;
        const int rA = wm + (lane & 15);
        const int rB = wn + (lane & 15);
        const int c = lane >> 4;
#pragma unroll
        for (int kk = 0; kk < T::BKm / 32; kk++) {
            bf16x8 av[4], bv[2];
#pragma unroll
            for (int mf = 0; mf < 4; mf++) {
                int row = rA + mf * 16;
                int sp = (kk * 4 + c) ^ (row & T::SWZ);
                av[mf] = __builtin_bit_cast(bf16x8,
                    *(const short8*)(As + row * T::RB + sp * 16));
            }
#pragma unroll
            for (int nf = 0; nf < 2; nf++) {
                int row = rB + nf * 16;
                int sp = (kk * 4 + c) ^ (row & T::SWZ);
                bv[nf] = __builtin_bit_cast(bf16x8,
                    *(const short8*)(Bs + row * T::RB + sp * 16));
            }
#pragma unroll
            for (int mf = 0; mf < 4; mf++)
#pragma unroll
                for (int nf = 0; nf < 2; nf++)
                    acc[mf][nf] = __builtin_amdgcn_mfma_f32_16x16x32_bf16(
                        av[mf], bv[nf], acc[mf][nf], 0, 0, 0);
        }
    };

    stage(0, 0);
    asm volatile("s_waitcnt vmcnt(0)" ::: "memory");
    __syncthreads();
    for (int it = 0; it < T::NIT; it++) {
        int b = it & 1;
        if (it + 1 < T::NIT) stage(b ^ 1, it + 1);
        compute(b);
        asm volatile("s_waitcnt vmcnt(0)" ::: "memory");
        __syncthreads();
    }
}

// Channel-mix: 9 interleaved planes [n][9][H] @ Wt-part -> output.
// LAYOUT 0: standard [n][9][H] (T / dX planes, feeds mix/final A-staging).
// LAYOUT 1: gather-optimized pair records [n][64][24]:
//   elem (n, h, c) at n*NPY + (h>>1)*24 + c*2 + (h&1)  (6 pad elems/record,
//   48-B aligned records -> gather reads Y as uint4+uint4+u32, 3 loads not 9).
template <int LAYOUT>
__global__ __launch_bounds__(256) void k_mix(
        const __hip_bfloat16* __restrict__ Db, const __hip_bfloat16* __restrict__ Wtb,
        __hip_bfloat16* __restrict__ Outp, int partOff) {
    __shared__ char lds[2 * TGm::LDSB];
    int c = blockIdx.z;
    int part = (c == 0) ? 0 : ((c < 4) ? 1 : 2);
    const __hip_bfloat16* A = Db + (size_t)c * H;
    const __hip_bfloat16* W = Wtb + (size_t)(partOff + part) * H * H;
    unsigned short* O = (unsigned short*)Outp;
    const int lane = threadIdx.x & 63;
    const int w = threadIdx.x >> 6;
    const int wm = (w & 1) * 64, wn = (w >> 1) * 32;
    const int m0 = blockIdx.x * 128, n0 = blockIdx.y * 64;
    f32x4 acc[4][2] = {};
    tile_gemm_mix(A, NP, W, m0, n0, lds, acc);
#pragma unroll
    for (int mf = 0; mf < 4; mf++)
#pragma unroll
        for (int r = 0; r < 4; r++) {
            int row = m0 + wm + mf * 16 + (lane >> 4) * 4 + r;
#pragma unroll
            for (int nf = 0; nf < 2; nf++) {
                int col = n0 + wn + nf * 16 + (lane & 15);
                if (LAYOUT == 0)
                    O[(size_t)row * NP + (size_t)c * H + col] = f2b(acc[mf][nf][r]);
                else
                    O[(size_t)row * NPY + (col >> 1) * 24 + c * 2 + (col & 1)] =
                        f2b(acc[mf][nf][r]);
            }
        }
}

// ---------------------------------------------------------------------------
// Fused 3-stage edge MLP, both layers (blockIdx.z), 64 edges per block,
// 512 threads / 8 waves. Swapped-operand MFMA, LDS lifetime-overlap (34.3 KB),
// lgkm-only barriers + cross-phase weight preload. (setprio removed: T5 is
// null without phase role-split — confirmed R7-R13.)
#define ETILE 64
#define PAD0 40     // sEA row stride (elements)
#define PAD1 136    // act1 row stride
#define PAD2 264    // act2 row stride
#define SA2_B (ETILE * PAD2 * 2)   // 33792 bytes: act2 region (base)
#define SA1_B (ETILE * PAD1 * 2)   // 17408 bytes: act1 (at base, inside act2)
#define SEA_OFF SA1_B              // sEA right after act1 (inside act2 region)

__global__ __launch_bounds__(512, 4) void k_mlp_fused(
        const __hip_bfloat16* __restrict__ eaB,
        const __hip_bfloat16* __restrict__ W1b, const __hip_bfloat16* __restrict__ W2b,
        const __hip_bfloat16* __restrict__ W3b,
        const float* __restrict__ bs1, const float* __restrict__ bs2,
        const float* __restrict__ bs3, const float* __restrict__ ew,
        __hip_bfloat16* __restrict__ ea3g) {
    const int l = blockIdx.z;
    const unsigned short* W1 = (const unsigned short*)W1b + (size_t)l * (H * R);
    const unsigned short* W2 = (const unsigned short*)W2b + (size_t)l * (2 * H * H);
    const unsigned short* W3 = (const unsigned short*)W3b + (size_t)l * (3 * H * 2 * H);
    const float* b1 = bs1 + (size_t)l * H;
    const float* b2 = bs2 + (size_t)l * 2 * H;
    const float* b3 = bs3 + (size_t)l * 3 * H;
    unsigned short* outp = (unsigned short*)ea3g + (size_t)l * NEDGES * 384;
    const int e0 = blockIdx.x * ETILE;

    __shared__ char smem[SA2_B + ETILE * 4 + 16];
    unsigned short* sA2 = (unsigned short*)smem;               // [64][PAD2]
    unsigned short* sA1 = (unsigned short*)smem;               // [64][PAD1] at base
    unsigned short* sEA = (unsigned short*)(smem + SEA_OFF);   // [64][PAD0]
    float* sEW = (float*)(smem + SA2_B);                       // ew cache

    const int t = threadIdx.x;
    const int lane = t & 63;
    const int w = t >> 6;        // 0..7
    const int q = lane >> 4;     // k-chunk index (0..3)
    const int li = lane & 15;

    const int cbase1 = w * 16;
    const int cbase2 = w * 32;
    const int cbase3 = w * 48;

    // Early global issues (independent of LDS): W1 fragment + bias1.
    bf16x8 av1 = __builtin_bit_cast(bf16x8,
        *(const short8*)(W1 + (size_t)(cbase1 + li) * R + q * 8));
    f32x4 bb1 = *(const f32x4*)&b1[cbase1 + q * 4];

    // stage edge_attr tile [64][32] + ew tile
    {
        if (t < 256) {
            int row = t >> 2, c8 = t & 3;
            *(uint4*)(sEA + row * PAD0 + c8 * 8) =
                *(const uint4*)((const unsigned short*)eaB + (size_t)(e0 + row) * R + c8 * 8);
        }
        if (t < ETILE) sEW[t] = ew[e0 + t];
    }
    BAR_LGKM();                                       // (1) sEA/sEW visible

    // ---- GEMM1: W1[128,32] @ ea^T -> act1^T ----
    f32x4 acc1[4] = {};
#pragma unroll
    for (int ef = 0; ef < 4; ef++) {
        bf16x8 bv = __builtin_bit_cast(bf16x8,
            *(const short8*)(sEA + (ef * 16 + li) * PAD0 + q * 8));
        acc1[ef] = __builtin_amdgcn_mfma_f32_16x16x32_bf16(av1, bv, acc1[ef], 0, 0, 0);
    }

    // Issue ALL GEMM2 weights now — they fly across GEMM1 epilogue + barrier.
    bf16x8 a2[4][2];
#pragma unroll
    for (int ks = 0; ks < 4; ks++)
#pragma unroll
        for (int mf = 0; mf < 2; mf++)
            a2[ks][mf] = __builtin_bit_cast(bf16x8,
                *(const short8*)(W2 + (size_t)(cbase2 + mf * 16 + li) * H
                                 + ks * 32 + q * 8));
    f32x4 bb2[2];
#pragma unroll
    for (int mf = 0; mf < 2; mf++)
        bb2[mf] = *(const f32x4*)&b2[cbase2 + mf * 16 + q * 4];

    // GEMM1 epilogue (writes act1 region [0..SA1_B), disjoint from sEA)
#pragma unroll
    for (int ef = 0; ef < 4; ef++) {
        u16x4 o;
#pragma unroll
        for (int r = 0; r < 4; r++) o[r] = f2b(silu_f(acc1[ef][r] + bb1[r]));
        *(u16x4*)(sA1 + (ef * 16 + li) * PAD1 + cbase1 + q * 4) = o;
    }
    BAR_LGKM();                                       // (2) act1 visible

    // ---- GEMM2: W2[256,128] @ act1^T -> act2^T (weights all in regs) ----
    f32x4 acc2[2][4] = {};
#pragma unroll
    for (int ks = 0; ks < 4; ks++) {
        bf16x8 bv[4];
#pragma unroll
        for (int ef = 0; ef < 4; ef++)
            bv[ef] = __builtin_bit_cast(bf16x8,
                *(const short8*)(sA1 + (ef * 16 + li) * PAD1 + ks * 32 + q * 8));
#pragma unroll
        for (int mf = 0; mf < 2; mf++)
#pragma unroll
            for (int ef = 0; ef < 4; ef++)
                acc2[mf][ef] = __builtin_amdgcn_mfma_f32_16x16x32_bf16(
                    a2[ks][mf], bv[ef], acc2[mf][ef], 0, 0, 0);
    }

    // Issue GEMM3's first 3 k-slice weights — fly across epilogue + 2 barriers.
    bf16x8 a3[3][3];   // [ks%3][mf]
#pragma unroll
    for (int pk = 0; pk < 3; pk++)
#pragma unroll
        for (int mf = 0; mf < 3; mf++)
            a3[pk][mf] = __builtin_bit_cast(bf16x8,
                *(const short8*)(W3 + (size_t)(cbase3 + mf * 16 + li) * (2 * H)
                                 + pk * 32 + q * 8));

    BAR_LGKM();   // (3) all act1/sEA reads done; safe to overwrite with act2
#pragma unroll
    for (int mf = 0; mf < 2; mf++)
#pragma unroll
        for (int ef = 0; ef < 4; ef++) {
            u16x4 o;
#pragma unroll
            for (int r = 0; r < 4; r++)
                o[r] = f2b(silu_f(acc2[mf][ef][r] + bb2[mf][r]));
            *(u16x4*)(sA2 + (ef * 16 + li) * PAD2 + cbase2 + mf * 16 + q * 4) = o;
        }
    BAR_LGKM();                                       // (4) act2 visible

    // ---- GEMM3: W3[384,256] @ act2^T, 3-deep rotating weight prefetch ----
    f32x4 acc3[3][4] = {};
#pragma unroll
    for (int ks = 0; ks < 8; ks++) {
        const int slot = ks % 3;
        bf16x8 bv[4];
#pragma unroll
        for (int ef = 0; ef < 4; ef++)
            bv[ef] = __builtin_bit_cast(bf16x8,
                *(const short8*)(sA2 + (ef * 16 + li) * PAD2 + ks * 32 + q * 8));
#pragma unroll
        for (int mf = 0; mf < 3; mf++)
#pragma unroll
            for (int ef = 0; ef < 4; ef++)
                acc3[mf][ef] = __builtin_amdgcn_mfma_f32_16x16x32_bf16(
                    a3[slot][mf], bv[ef], acc3[mf][ef], 0, 0, 0);
        if (ks + 3 < 8) {   // reload this slot for iteration ks+3
#pragma unroll
            for (int mf = 0; mf < 3; mf++)
                a3[slot][mf] = __builtin_bit_cast(bf16x8,
                    *(const short8*)(W3 + (size_t)(cbase3 + mf * 16 + li) * (2 * H)
                                     + (ks + 3) * 32 + q * 8));
        }
    }
    f32x4 bb3[3];
#pragma unroll
    for (int mf = 0; mf < 3; mf++)
        bb3[mf] = *(const f32x4*)&b3[cbase3 + mf * 16 + q * 4];
#pragma unroll
    for (int ef = 0; ef < 4; ef++) {
        int edge = ef * 16 + li;
        float wv = sEW[edge];
        float cs = (wv < CUTOFF_F) ? 0.5f * (__cosf(wv * PI_OVER_CUTOFF) + 1.f) : 0.f;
#pragma unroll
        for (int mf = 0; mf < 3; mf++) {
            u16x4 o;
#pragma unroll
            for (int r = 0; r < 4; r++)
                o[r] = f2b(silu_f(acc3[mf][ef][r] + bb3[mf][r]) * cs);
            *(u16x4*)(outp + (size_t)(e0 + edge) * 384 + cbase3 + mf * 16 + q * 4) = o;
        }
    }
}

// ---------------------------------------------------------------------------
// CSR build (once; edge_index is static across layers)
__global__ __launch_bounds__(256) void k_hist(
        const int* __restrict__ eidx, int* __restrict__ cnt) {
    int e = blockIdx.x * 256 + threadIdx.x;
    if (e < NEDGES) atomicAdd(&cnt[eidx[e]], 1);
}

__global__ __launch_bounds__(256) void k_scan(
        const int* __restrict__ cnt, int* __restrict__ rowstart,
        int* __restrict__ cursor) {
    __shared__ int partial[256];
    int t = threadIdx.x;
    int loc[8];
    int run = 0;
#pragma unroll
    for (int j = 0; j < 8; j++) {
        int v = cnt[t * 8 + j];
        loc[j] = run; run += v;
    }
    partial[t] = run;
    __syncthreads();
    if (t == 0) {
        int acc = 0;
        for (int i = 0; i < 256; i++) { int v = partial[i]; partial[i] = acc; acc += v; }
        rowstart[2048] = acc;
    }
    __syncthreads();
    int base = partial[t];
#pragma unroll
    for (int j = 0; j < 8; j++) {
        rowstart[t * 8 + j] = base + loc[j];
        cursor[t * 8 + j] = base + loc[j];
    }
}

__global__ __launch_bounds__(256) void k_fill(
        const int* __restrict__ eidx, int* __restrict__ cursor,
        int* __restrict__ elist) {
    int e = blockIdx.x * 256 + threadIdx.x;
    if (e >= NEDGES) return;
    int src = eidx[e];
    int pos = atomicAdd(&cursor[src], 1);
    elist[pos] = e;
}

// ---------------------------------------------------------------------------
// Gather + fused abnorm v3: NH*2 threads; 4 lanes per (node, h-pair) split the
// edge list (4x TLP), Y read as pair-records (3 vector loads, not 9 scalar),
// 2-step shfl_xor combine, abnorm on quarters 0/1.
__global__ __launch_bounds__(256) void k_gather_ab(
        const __hip_bfloat16* __restrict__ ea /* [E][384], col=h*3+comp */,
        const int* __restrict__ eidx,
        const int* __restrict__ rowstart, const int* __restrict__ elist,
        const __hip_bfloat16* __restrict__ Yb /* [n][64][24] pair records */,
        const float* __restrict__ q,
        __hip_bfloat16* __restrict__ Tb /* [n][9][H] */) {
    int gid = blockIdx.x * 256 + threadIdx.x;   // NH*2 threads
    int n = gid >> 8;
    int t8 = gid & 255;
    int hp = t8 >> 2;          // h-pair 0..63
    int quarter = t8 & 3;      // edge-list quarter
    int h0 = hp << 1;
    int beg = rowstart[n], end = rowstart[n + 1];
    const unsigned short* Y = (const unsigned short*)Yb;

    float acc[9][2];
#pragma unroll
    for (int c = 0; c < 9; c++) { acc[c][0] = 0.f; acc[c][1] = 0.f; }

    int idx = beg + quarter;
    int e = 0, dst = 0;
    if (idx < end) { e = elist[idx]; dst = eidx[NEDGES + e]; }
    while (idx < end) {
        int nidx = idx + 4;
        int ne = e, ndst = dst;
        if (nidx < end) { ne = elist[nidx]; ndst = eidx[NEDGES + ne]; }
        const unsigned short* eap = (const unsigned short*)ea + (size_t)e * 384 + h0 * 3;
        unsigned u0 = *(const unsigned*)(eap);
        unsigned u1 = *(const unsigned*)(eap + 2);
        unsigned u2 = *(const unsigned*)(eap + 4);
        float w0a = b2f_lo(u0), w1a = b2f_hi(u0);
        float w2a = b2f_lo(u1), w0b = b2f_hi(u1);
        float w1b = b2f_lo(u2), w2b = b2f_hi(u2);
        const unsigned short* yr = Y + (size_t)dst * NPY + hp * 24;
        uint4 ya = *(const uint4*)yr;          // comps 0..3 (lo=h0, hi=h1)
        uint4 yb = *(const uint4*)(yr + 8);    // comps 4..7
        unsigned yc = *(const unsigned*)(yr + 16);  // comp 8
        acc[0][0] += w0a * b2f_lo(ya.x); acc[0][1] += w0b * b2f_hi(ya.x);
        acc[1][0] += w1a * b2f_lo(ya.y); acc[1][1] += w1b * b2f_hi(ya.y);
        acc[2][0] += w1a * b2f_lo(ya.z); acc[2][1] += w1b * b2f_hi(ya.z);
        acc[3][0] += w1a * b2f_lo(ya.w); acc[3][1] += w1b * b2f_hi(ya.w);
        acc[4][0] += w2a * b2f_lo(yb.x); acc[4][1] += w2b * b2f_hi(yb.x);
        acc[5][0] += w2a * b2f_lo(yb.y); acc[5][1] += w2b * b2f_hi(yb.y);
        acc[6][0] += w2a * b2f_lo(yb.z); acc[6][1] += w2b * b2f_hi(yb.z);
        acc[7][0] += w2a * b2f_lo(yb.w); acc[7][1] += w2b * b2f_hi(yb.w);
        acc[8][0] += w2a * b2f_lo(yc);   acc[8][1] += w2b * b2f_hi(yc);
        idx = nidx; e = ne; dst = ndst;
    }
    // combine the four quarters (lanes differ in bits 0..1)
#pragma unroll
    for (int c = 0; c < 9; c++) {
        acc[c][0] += __shfl_xor(acc[c][0], 1);
        acc[c][1] += __shfl_xor(acc[c][1], 1);
        acc[c][0] += __shfl_xor(acc[c][0], 2);
        acc[c][1] += __shfl_xor(acc[c][1], 2);
    }
    if (quarter >= 2) return;
    // fused abnorm: quarter 0 -> col h0, quarter 1 -> col h0+1
    int hcol = h0 + quarter;
    const unsigned short* yr = Y + (size_t)n * NPY + hp * 24;
    float scale = 1.f + 0.1f * q[n];
    float md[9], yd[9];
#pragma unroll
    for (int c = 0; c < 9; c++) {
        md[c] = acc[c][quarter];
        yd[c] = b2f(yr[c * 2 + quarter]);
    }
    float m[9], yf[9];
    build_full(md, m);
    build_full(yd, yf);
    float ab[9];
#pragma unroll
    for (int ii = 0; ii < 3; ii++)
#pragma unroll
        for (int jj = 0; jj < 3; jj++) {
            float s = 0.f;
#pragma unroll
            for (int kk = 0; kk < 3; kk++)
                s += m[ii * 3 + kk] * yf[kk * 3 + jj] + yf[ii * 3 + kk] * m[kk * 3 + jj];
            ab[ii * 3 + jj] = s;
        }
    float nrm = 0.f;
#pragma unroll
    for (int j = 0; j < 9; j++) { ab[j] *= scale; nrm += ab[j] * ab[j]; }
    float inv = 1.f / (nrm + 1.f);
    float tr3 = (ab[0] + ab[4] + ab[8]) * (1.f / 3.f);
    unsigned short* T = (unsigned short*)Tb + (size_t)n * NP + hcol;
    T[0 * H] = f2b(tr3 * inv);
    T[1 * H] = f2b(0.5f * (ab[1] - ab[3]) * inv);
    T[2 * H] = f2b(0.5f * (ab[2] - ab[6]) * inv);
    T[3 * H] = f2b(0.5f * (ab[5] - ab[7]) * inv);
    T[4 * H] = f2b((ab[0] - tr3) * inv);
    T[5 * H] = f2b(0.5f * (ab[1] + ab[3]) * inv);
    T[6 * H] = f2b(0.5f * (ab[2] + ab[6]) * inv);
    T[7 * H] = f2b((ab[4] - tr3) * inv);
    T[8 * H] = f2b(0.5f * (ab[5] + ab[7]) * inv);
}

// ---------------------------------------------------------------------------
// Final: Xout = Xn + dX + (1+0.1q)*dX@dX.  dX interleaved bf16 [n][9][H].
// PREP: also normalize+decompose Xout into Xn (fp32) and Db (bf16) for next layer.
template <bool PREP>
__global__ __launch_bounds__(256) void k_final(
        const __hip_bfloat16* __restrict__ dXb, const float* __restrict__ Xn,
        const float* __restrict__ q, float* __restrict__ Xout,
        float* __restrict__ XnW, __hip_bfloat16* __restrict__ Db) {
    int i = blockIdx.x * 256 + threadIdx.x;
    if (i >= NH) return;
    const unsigned short* dX = (const unsigned short*)dXb + (size_t)(i >> 7) * NP + (i & 127);
    float dd[9];
#pragma unroll
    for (int c = 0; c < 9; c++) dd[c] = b2f(dX[(size_t)c * H]);
    float dx[9];
    build_full(dd, dx);
    float scale = 1.f + 0.1f * q[i >> 7];
    float out[9];
#pragma unroll
    for (int ii = 0; ii < 3; ii++)
#pragma unroll
        for (int jj = 0; jj < 3; jj++) {
            float s = 0.f;
#pragma unroll
            for (int kk = 0; kk < 3; kk++)
                s += dx[ii * 3 + kk] * dx[kk * 3 + jj];
            out[ii * 3 + jj] = Xn[(size_t)i * 9 + ii * 3 + jj] + dx[ii * 3 + jj] + scale * s;
        }
#pragma unroll
    for (int j = 0; j < 9; j++) Xout[(size_t)i * 9 + j] = out[j];
    if (PREP) {
        float ss = 0.f;
#pragma unroll
        for (int j = 0; j < 9; j++) ss += out[j] * out[j];
        float inv = 1.f / (ss + 1.f);
        float v[9];
#pragma unroll
        for (int j = 0; j < 9; j++) { v[j] = out[j] * inv; XnW[(size_t)i * 9 + j] = v[j]; }
        float i0 = (v[0] + v[4] + v[8]) * (1.f / 3.f);
        unsigned short* D = (unsigned short*)Db + (size_t)(i >> 7) * NP + (i & 127);
        D[0 * H] = f2b(i0);
        D[1 * H] = f2b(0.5f * (v[1] - v[3]));
        D[2 * H] = f2b(0.5f * (v[2] - v[6]));
        D[3 * H] = f2b(0.5f * (v[5] - v[7]));
        D[4 * H] = f2b(v[0] - i0);
        D[5 * H] = f2b(0.5f * (v[1] + v[3]));
        D[6 * H] = f2b(0.5f * (v[2] + v[6]));
        D[7 * H] = f2b(v[4] - i0);
        D[8 * H] = f2b(0.5f * (v[5] + v[7]));
    }
}

// ---------------------------------------------------------------------------
extern "C" void kernel_launch(void* const* d_in, const int* in_sizes, int n_in,
                              void* d_out, int out_size, void* d_ws, size_t ws_size,
                              hipStream_t stream) {
    const float* X          = (const float*)d_in[0];
    const float* edge_attr  = (const float*)d_in[1];
    const float* edge_weight= (const float*)d_in[2];
    const float* q          = (const float*)d_in[3];
    const float* Ws1        = (const float*)d_in[4];
    const float* bs1        = (const float*)d_in[5];
    const float* Ws2        = (const float*)d_in[6];
    const float* bs2        = (const float*)d_in[7];
    const float* Ws3        = (const float*)d_in[8];
    const float* bs3        = (const float*)d_in[9];
    const float* Wt         = (const float*)d_in[10];
    const int*   eidx       = (const int*)d_in[11];
    float* Xout = (float*)d_out;

    char* p = (char*)d_ws;
    auto alloc = [&](size_t bytes) -> char* {
        char* r = p; p += (bytes + 255) & ~(size_t)255; return r;
    };
    size_t nodeBytes = (size_t)NH * 9 * sizeof(float);
    float* Xn   = (float*)alloc(nodeBytes);
    __hip_bfloat16* Db = (__hip_bfloat16*)alloc((size_t)NH * 9 * 2);     // D / T planes
    __hip_bfloat16* Yb = (__hip_bfloat16*)alloc((size_t)NATOMS * NPY * 2); // Y pair records / dX planes
    __hip_bfloat16* eaB = (__hip_bfloat16*)alloc((size_t)C0 * 2);
    __hip_bfloat16* W1b = (__hip_bfloat16*)alloc((size_t)C1 * 2);
    __hip_bfloat16* W2b = (__hip_bfloat16*)alloc((size_t)C2 * 2);
    __hip_bfloat16* W3b = (__hip_bfloat16*)alloc((size_t)C3 * 2);
    __hip_bfloat16* Wtb = (__hip_bfloat16*)alloc((size_t)C4 * 2);
    __hip_bfloat16* ea3g = (__hip_bfloat16*)alloc((size_t)2 * NEDGES * 384 * 2);
    int* cnt      = (int*)alloc(2048 * 4);
    int* rowstart = (int*)alloc(2049 * 4);
    int* cursor   = (int*)alloc(2048 * 4);
    int* elist    = (int*)alloc(NEDGES * 4);

    // one-time bf16 casts + cnt zeroing + node prep (fused)
    k_cast_all<<<(CAST_TOTAL + 255) / 256, 256, 0, stream>>>(
        edge_attr, Ws1, Ws2, Ws3, Wt, eaB, W1b, W2b, W3b, Wtb, cnt,
        X, Xn, Db);

    // CSR once (edge_index static across layers)
    k_hist<<<NEDGES / 256, 256, 0, stream>>>(eidx, cnt);
    k_scan<<<1, 256, 0, stream>>>(cnt, rowstart, cursor);
    k_fill<<<NEDGES / 256, 256, 0, stream>>>(eidx, cursor, elist);

    // edge MLP for BOTH layers in one launch (independent of X)
    k_mlp_fused<<<dim3(NEDGES / ETILE, 1, 2), 512, 0, stream>>>(
        eaB, W1b, W2b, W3b, bs1, bs2, bs3, edge_weight, ea3g);

    for (int l = 0; l < 2; l++) {
        const __hip_bfloat16* Wtl = Wtb + (size_t)l * 6 * H * H;
        const __hip_bfloat16* ea3 = ea3g + (size_t)l * NEDGES * 384;

        // Y = chan_mix(decomposed Xn) -> pair-record layout
        k_mix<1><<<dim3(NATOMS / 128, 2, 9), 256, 0, stream>>>(Db, Wtl, Yb, 0);
        // gather + fused abnorm -> Tb (reuses Db)
        k_gather_ab<<<(NH * 2) / 256, 256, 0, stream>>>(
            ea3, eidx, rowstart, elist, Yb, q, Db);
        // dX = chan_mix(T) -> standard planes (reuses Yb)
        k_mix<0><<<dim3(NATOMS / 128, 2, 9), 256, 0, stream>>>(Db, Wtl, Yb, 3);
        // final (+ fused node-prep for next layer)
        if (l == 0)
            k_final<true><<<NH / 256, 256, 0, stream>>>(Yb, Xn, q, Xout, Xn, Db);
        else
            k_final<false><<<NH / 256, 256, 0, stream>>>(Yb, Xn, q, Xout, nullptr, nullptr);
    }
}

// Round 15
// 156.543 us; speedup vs baseline: 1.0871x; 1.0871x over previous
//
#include <hip/hip_runtime.h>
#include <hip/hip_bf16.h>
#include <math.h>

#define H 128
#define R 32
#define NATOMS 2048
#define NEDGES 32768
#define NH (NATOMS * H)          // 262144 (n,h) pairs
#define NP 1152                  // 9*H: node-plane row stride (interleaved [n][9][H])
#define CUTOFF_F 4.5f
#define PI_OVER_CUTOFF 0.6981317007977318f

typedef __bf16 bf16x8 __attribute__((ext_vector_type(8)));
typedef float f32x4 __attribute__((ext_vector_type(4)));
typedef short short8 __attribute__((ext_vector_type(8)));
typedef unsigned short u16x4 __attribute__((ext_vector_type(4)));

// lgkm-only barrier: LDS visible, global loads stay in flight across it.
#define BAR_LGKM() do { \
    asm volatile("s_waitcnt lgkmcnt(0)" ::: "memory"); \
    __builtin_amdgcn_s_barrier(); \
    asm volatile("" ::: "memory"); \
} while (0)

// ---------------------------------------------------------------------------
__device__ __forceinline__ float silu_f(float x) {
    return x / (1.f + __expf(-x));
}
__device__ __forceinline__ float b2f(unsigned short u) {
    return __uint_as_float(((unsigned)u) << 16);
}
__device__ __forceinline__ unsigned short f2b(float f) {
    __hip_bfloat16 h = __float2bfloat16(f);
    return __builtin_bit_cast(unsigned short, h);
}

// Build full 3x3 from decomposition [i0, a01, a02, a12, s00, s01, s02, s11, s12]
__device__ __forceinline__ void build_full(const float d[9], float m[9]) {
    float i0 = d[0], a01 = d[1], a02 = d[2], a12 = d[3];
    float s00 = d[4], s01 = d[5], s02 = d[6], s11 = d[7], s12 = d[8];
    float s22 = -(s00 + s11);
    m[0] = i0 + s00;  m[1] = a01 + s01;  m[2] = a02 + s02;
    m[3] = s01 - a01; m[4] = i0 + s11;   m[5] = a12 + s12;
    m[6] = s02 - a02; m[7] = s12 - a12;  m[8] = i0 + s22;
}

// ---------------------------------------------------------------------------
// One-shot cast of all fp32 params to bf16 + CSR cnt zeroing + node prep
#define C0 (NEDGES * R)          // edge_attr
#define C1 (2 * H * R)           // Ws1
#define C2 (2 * 2 * H * H)       // Ws2
#define C3 (2 * 3 * H * 2 * H)   // Ws3
#define C4 (2 * 6 * H * H)       // Wt
#define C5 2048                  // cnt zero
#define CAST_TOTAL (C0 + C1 + C2 + C3 + C4 + C5 + NH)
__global__ __launch_bounds__(256) void k_cast_all(
        const float* __restrict__ ea, const float* __restrict__ w1,
        const float* __restrict__ w2, const float* __restrict__ w3,
        const float* __restrict__ wt,
        __hip_bfloat16* __restrict__ oea, __hip_bfloat16* __restrict__ ow1,
        __hip_bfloat16* __restrict__ ow2, __hip_bfloat16* __restrict__ ow3,
        __hip_bfloat16* __restrict__ owt, int* __restrict__ cnt,
        const float* __restrict__ X, float* __restrict__ Xn,
        __hip_bfloat16* __restrict__ Db) {
    int i = blockIdx.x * 256 + threadIdx.x;
    if (i < C0) { oea[i] = __float2bfloat16(ea[i]); return; }
    i -= C0;
    if (i < C1) { ow1[i] = __float2bfloat16(w1[i]); return; }
    i -= C1;
    if (i < C2) { ow2[i] = __float2bfloat16(w2[i]); return; }
    i -= C2;
    if (i < C3) { ow3[i] = __float2bfloat16(w3[i]); return; }
    i -= C3;
    if (i < C4) { owt[i] = __float2bfloat16(wt[i]); return; }
    i -= C4;
    if (i < C5) { cnt[i] = 0; return; }
    i -= C5;
    if (i < NH) {
        const float* x = X + (size_t)i * 9;
        float v[9];
        float ss = 0.f;
#pragma unroll
        for (int j = 0; j < 9; j++) { v[j] = x[j]; ss += v[j] * v[j]; }
        float inv = 1.f / (ss + 1.f);
#pragma unroll
        for (int j = 0; j < 9; j++) { v[j] *= inv; Xn[(size_t)i * 9 + j] = v[j]; }
        float i0 = (v[0] + v[4] + v[8]) * (1.f / 3.f);
        unsigned short* D = (unsigned short*)Db + (size_t)(i >> 7) * NP + (i & 127);
        D[0 * H] = f2b(i0);
        D[1 * H] = f2b(0.5f * (v[1] - v[3]));
        D[2 * H] = f2b(0.5f * (v[2] - v[6]));
        D[3 * H] = f2b(0.5f * (v[5] - v[7]));
        D[4 * H] = f2b(v[0] - i0);
        D[5 * H] = f2b(0.5f * (v[1] + v[3]));
        D[6 * H] = f2b(0.5f * (v[2] + v[6]));
        D[7 * H] = f2b(v[4] - i0);
        D[8 * H] = f2b(0.5f * (v[5] + v[7]));
    }
}

// ---------------------------------------------------------------------------
// bf16 MFMA 128x64 tile-GEMM core for the channel mix (K=128), strided A.
struct TGm {
    static constexpr int BKm = 64;
    static constexpr int RB  = 128;        // row bytes per K-step
    static constexpr int SWZ = 7;
    static constexpr int NIT = 2;
    static constexpr int ABYTES = 128 * RB;
    static constexpr int BBYTES = 64 * RB;
    static constexpr int AISS = ABYTES / 4096;
    static constexpr int BISS = BBYTES / 4096;
    static constexpr int LDSB = ABYTES + BBYTES;
};

__device__ __forceinline__ void tile_gemm_mix(
        const __hip_bfloat16* __restrict__ A, int strideA,
        const __hip_bfloat16* __restrict__ W,
        int m0, int n0, char* lds, f32x4 acc[4][2]) {
    using T = TGm;
    const int t = threadIdx.x;
    const int lane = t & 63;
    const int w = t >> 6;

    auto stage = [&](int b, int it) {
        const int k0 = it * T::BKm;
        char* As = lds + b * T::LDSB;
        char* Bs = As + T::ABYTES;
#pragma unroll
        for (int i = 0; i < T::AISS; i++) {
            int base = (w * T::AISS + i) * 1024;
            int lin = base + lane * 16;
            int row = lin / T::RB;
            int slot = (lin % T::RB) >> 4;
            int sl = slot ^ (row & T::SWZ);
            const char* src = (const char*)(A + (size_t)(m0 + row) * strideA + k0) + sl * 16;
            __builtin_amdgcn_global_load_lds(
                (const __attribute__((address_space(1))) void*)src,
                (__attribute__((address_space(3))) void*)(As + base), 16, 0, 0);
        }
#pragma unroll
        for (int i = 0; i < T::BISS; i++) {
            int base = (w * T::BISS + i) * 1024;
            int lin = base + lane * 16;
            int row = lin / T::RB;
            int slot = (lin % T::RB) >> 4;
            int sl = slot ^ (row & T::SWZ);
            const char* src = (const char*)(W + (size_t)(n0 + row) * H + k0) + sl * 16;
            __builtin_amdgcn_global_load_lds(
                (const __attribute__((address_space(1))) void*)src,
                (__attribute__((address_space(3))) void*)(Bs + base), 16, 0, 0);
        }
    };

    auto compute = [&](int b) {
        const char* As = lds + b * T::LDSB;
        const char* Bs = As + T::ABYTES;
        const int wm = (w & 1) * 64;
        const int wn = (w >> 1) * 32;
        const int rA = wm + (lane & 15);
        const int rB = wn + (lane & 15);
        const int c = lane >> 4;
#pragma unroll
        for (int kk = 0; kk < T::BKm / 32; kk++) {
            bf16x8 av[4], bv[2];
#pragma unroll
            for (int mf = 0; mf < 4; mf++) {
                int row = rA + mf * 16;
                int sp = (kk * 4 + c) ^ (row & T::SWZ);
                av[mf] = __builtin_bit_cast(bf16x8,
                    *(const short8*)(As + row * T::RB + sp * 16));
            }
#pragma unroll
            for (int nf = 0; nf < 2; nf++) {
                int row = rB + nf * 16;
                int sp = (kk * 4 + c) ^ (row & T::SWZ);
                bv[nf] = __builtin_bit_cast(bf16x8,
                    *(const short8*)(Bs + row * T::RB + sp * 16));
            }
#pragma unroll
            for (int mf = 0; mf < 4; mf++)
#pragma unroll
                for (int nf = 0; nf < 2; nf++)
                    acc[mf][nf] = __builtin_amdgcn_mfma_f32_16x16x32_bf16(
                        av[mf], bv[nf], acc[mf][nf], 0, 0, 0);
        }
    };

    stage(0, 0);
    asm volatile("s_waitcnt vmcnt(0)" ::: "memory");
    __syncthreads();
    for (int it = 0; it < T::NIT; it++) {
        int b = it & 1;
        if (it + 1 < T::NIT) stage(b ^ 1, it + 1);
        compute(b);
        asm volatile("s_waitcnt vmcnt(0)" ::: "memory");
        __syncthreads();
    }
}

// Channel-mix: 9 interleaved planes [n][9][H] @ Wt-part [128][128] -> bf16 planes.
__global__ __launch_bounds__(256) void k_mix(
        const __hip_bfloat16* __restrict__ Db, const __hip_bfloat16* __restrict__ Wtb,
        __hip_bfloat16* __restrict__ Outp, int partOff) {
    __shared__ char lds[2 * TGm::LDSB];
    int c = blockIdx.z;
    int part = (c == 0) ? 0 : ((c < 4) ? 1 : 2);
    const __hip_bfloat16* A = Db + (size_t)c * H;
    const __hip_bfloat16* W = Wtb + (size_t)(partOff + part) * H * H;
    unsigned short* Out = (unsigned short*)Outp + (size_t)c * H;
    const int lane = threadIdx.x & 63;
    const int w = threadIdx.x >> 6;
    const int wm = (w & 1) * 64, wn = (w >> 1) * 32;
    const int m0 = blockIdx.x * 128, n0 = blockIdx.y * 64;
    f32x4 acc[4][2] = {};
    tile_gemm_mix(A, NP, W, m0, n0, lds, acc);
#pragma unroll
    for (int mf = 0; mf < 4; mf++)
#pragma unroll
        for (int r = 0; r < 4; r++) {
            int row = m0 + wm + mf * 16 + (lane >> 4) * 4 + r;
#pragma unroll
            for (int nf = 0; nf < 2; nf++) {
                int col = n0 + wn + nf * 16 + (lane & 15);
                Out[(size_t)row * NP + col] = f2b(acc[mf][nf][r]);
            }
        }
}

// ---------------------------------------------------------------------------
// Fused 3-stage edge MLP, both layers (blockIdx.z), 64 edges per block,
// 512 threads / 8 waves. Swapped-operand MFMA, LDS lifetime-overlap (34.3 KB),
// lgkm-only barriers + cross-phase weight preload. No setprio (T5 null/harmful
// without phase role-split — measured R13->R14: 54.7 -> 52.3 us).
#define ETILE 64
#define PAD0 40     // sEA row stride (elements)
#define PAD1 136    // act1 row stride
#define PAD2 264    // act2 row stride
#define SA2_B (ETILE * PAD2 * 2)   // 33792 bytes: act2 region (base)
#define SA1_B (ETILE * PAD1 * 2)   // 17408 bytes: act1 (at base, inside act2)
#define SEA_OFF SA1_B              // sEA right after act1 (inside act2 region)

__global__ __launch_bounds__(512, 4) void k_mlp_fused(
        const __hip_bfloat16* __restrict__ eaB,
        const __hip_bfloat16* __restrict__ W1b, const __hip_bfloat16* __restrict__ W2b,
        const __hip_bfloat16* __restrict__ W3b,
        const float* __restrict__ bs1, const float* __restrict__ bs2,
        const float* __restrict__ bs3, const float* __restrict__ ew,
        __hip_bfloat16* __restrict__ ea3g) {
    const int l = blockIdx.z;
    const unsigned short* W1 = (const unsigned short*)W1b + (size_t)l * (H * R);
    const unsigned short* W2 = (const unsigned short*)W2b + (size_t)l * (2 * H * H);
    const unsigned short* W3 = (const unsigned short*)W3b + (size_t)l * (3 * H * 2 * H);
    const float* b1 = bs1 + (size_t)l * H;
    const float* b2 = bs2 + (size_t)l * 2 * H;
    const float* b3 = bs3 + (size_t)l * 3 * H;
    unsigned short* outp = (unsigned short*)ea3g + (size_t)l * NEDGES * 384;
    const int e0 = blockIdx.x * ETILE;

    __shared__ char smem[SA2_B + ETILE * 4 + 16];
    unsigned short* sA2 = (unsigned short*)smem;               // [64][PAD2]
    unsigned short* sA1 = (unsigned short*)smem;               // [64][PAD1] at base
    unsigned short* sEA = (unsigned short*)(smem + SEA_OFF);   // [64][PAD0]
    float* sEW = (float*)(smem + SA2_B);                       // ew cache

    const int t = threadIdx.x;
    const int lane = t & 63;
    const int w = t >> 6;        // 0..7
    const int q = lane >> 4;     // k-chunk index (0..3)
    const int li = lane & 15;

    const int cbase1 = w * 16;
    const int cbase2 = w * 32;
    const int cbase3 = w * 48;

    // Early global issues (independent of LDS): W1 fragment + bias1.
    bf16x8 av1 = __builtin_bit_cast(bf16x8,
        *(const short8*)(W1 + (size_t)(cbase1 + li) * R + q * 8));
    f32x4 bb1 = *(const f32x4*)&b1[cbase1 + q * 4];

    // stage edge_attr tile [64][32] + ew tile
    {
        if (t < 256) {
            int row = t >> 2, c8 = t & 3;
            *(uint4*)(sEA + row * PAD0 + c8 * 8) =
                *(const uint4*)((const unsigned short*)eaB + (size_t)(e0 + row) * R + c8 * 8);
        }
        if (t < ETILE) sEW[t] = ew[e0 + t];
    }
    BAR_LGKM();                                       // (1) sEA/sEW visible

    // ---- GEMM1: W1[128,32] @ ea^T -> act1^T ----
    f32x4 acc1[4] = {};
#pragma unroll
    for (int ef = 0; ef < 4; ef++) {
        bf16x8 bv = __builtin_bit_cast(bf16x8,
            *(const short8*)(sEA + (ef * 16 + li) * PAD0 + q * 8));
        acc1[ef] = __builtin_amdgcn_mfma_f32_16x16x32_bf16(av1, bv, acc1[ef], 0, 0, 0);
    }

    // Issue ALL GEMM2 weights now — they fly across GEMM1 epilogue + barrier.
    bf16x8 a2[4][2];
#pragma unroll
    for (int ks = 0; ks < 4; ks++)
#pragma unroll
        for (int mf = 0; mf < 2; mf++)
            a2[ks][mf] = __builtin_bit_cast(bf16x8,
                *(const short8*)(W2 + (size_t)(cbase2 + mf * 16 + li) * H
                                 + ks * 32 + q * 8));
    f32x4 bb2[2];
#pragma unroll
    for (int mf = 0; mf < 2; mf++)
        bb2[mf] = *(const f32x4*)&b2[cbase2 + mf * 16 + q * 4];

    // GEMM1 epilogue (writes act1 region [0..SA1_B), disjoint from sEA)
#pragma unroll
    for (int ef = 0; ef < 4; ef++) {
        u16x4 o;
#pragma unroll
        for (int r = 0; r < 4; r++) o[r] = f2b(silu_f(acc1[ef][r] + bb1[r]));
        *(u16x4*)(sA1 + (ef * 16 + li) * PAD1 + cbase1 + q * 4) = o;
    }
    BAR_LGKM();                                       // (2) act1 visible

    // ---- GEMM2: W2[256,128] @ act1^T -> act2^T (weights all in regs) ----
    f32x4 acc2[2][4] = {};
#pragma unroll
    for (int ks = 0; ks < 4; ks++) {
        bf16x8 bv[4];
#pragma unroll
        for (int ef = 0; ef < 4; ef++)
            bv[ef] = __builtin_bit_cast(bf16x8,
                *(const short8*)(sA1 + (ef * 16 + li) * PAD1 + ks * 32 + q * 8));
#pragma unroll
        for (int mf = 0; mf < 2; mf++)
#pragma unroll
            for (int ef = 0; ef < 4; ef++)
                acc2[mf][ef] = __builtin_amdgcn_mfma_f32_16x16x32_bf16(
                    a2[ks][mf], bv[ef], acc2[mf][ef], 0, 0, 0);
    }

    // Issue GEMM3's first 3 k-slice weights — fly across epilogue + 2 barriers.
    bf16x8 a3[3][3];   // [ks%3][mf]
#pragma unroll
    for (int pk = 0; pk < 3; pk++)
#pragma unroll
        for (int mf = 0; mf < 3; mf++)
            a3[pk][mf] = __builtin_bit_cast(bf16x8,
                *(const short8*)(W3 + (size_t)(cbase3 + mf * 16 + li) * (2 * H)
                                 + pk * 32 + q * 8));

    BAR_LGKM();   // (3) all act1/sEA reads done; safe to overwrite with act2
#pragma unroll
    for (int mf = 0; mf < 2; mf++)
#pragma unroll
        for (int ef = 0; ef < 4; ef++) {
            u16x4 o;
#pragma unroll
            for (int r = 0; r < 4; r++)
                o[r] = f2b(silu_f(acc2[mf][ef][r] + bb2[mf][r]));
            *(u16x4*)(sA2 + (ef * 16 + li) * PAD2 + cbase2 + mf * 16 + q * 4) = o;
        }
    BAR_LGKM();                                       // (4) act2 visible

    // ---- GEMM3: W3[384,256] @ act2^T, 3-deep rotating weight prefetch ----
    f32x4 acc3[3][4] = {};
#pragma unroll
    for (int ks = 0; ks < 8; ks++) {
        const int slot = ks % 3;
        bf16x8 bv[4];
#pragma unroll
        for (int ef = 0; ef < 4; ef++)
            bv[ef] = __builtin_bit_cast(bf16x8,
                *(const short8*)(sA2 + (ef * 16 + li) * PAD2 + ks * 32 + q * 8));
#pragma unroll
        for (int mf = 0; mf < 3; mf++)
#pragma unroll
            for (int ef = 0; ef < 4; ef++)
                acc3[mf][ef] = __builtin_amdgcn_mfma_f32_16x16x32_bf16(
                    a3[slot][mf], bv[ef], acc3[mf][ef], 0, 0, 0);
        if (ks + 3 < 8) {   // reload this slot for iteration ks+3
#pragma unroll
            for (int mf = 0; mf < 3; mf++)
                a3[slot][mf] = __builtin_bit_cast(bf16x8,
                    *(const short8*)(W3 + (size_t)(cbase3 + mf * 16 + li) * (2 * H)
                                     + (ks + 3) * 32 + q * 8));
        }
    }
    f32x4 bb3[3];
#pragma unroll
    for (int mf = 0; mf < 3; mf++)
        bb3[mf] = *(const f32x4*)&b3[cbase3 + mf * 16 + q * 4];
#pragma unroll
    for (int ef = 0; ef < 4; ef++) {
        int edge = ef * 16 + li;
        float wv = sEW[edge];
        float cs = (wv < CUTOFF_F) ? 0.5f * (__cosf(wv * PI_OVER_CUTOFF) + 1.f) : 0.f;
#pragma unroll
        for (int mf = 0; mf < 3; mf++) {
            u16x4 o;
#pragma unroll
            for (int r = 0; r < 4; r++)
                o[r] = f2b(silu_f(acc3[mf][ef][r] + bb3[mf][r]) * cs);
            *(u16x4*)(outp + (size_t)(e0 + edge) * 384 + cbase3 + mf * 16 + q * 4) = o;
        }
    }
}

// ---------------------------------------------------------------------------
// CSR build (once; edge_index is static across layers)
__global__ __launch_bounds__(256) void k_hist(
        const int* __restrict__ eidx, int* __restrict__ cnt) {
    int e = blockIdx.x * 256 + threadIdx.x;
    if (e < NEDGES) atomicAdd(&cnt[eidx[e]], 1);
}

__global__ __launch_bounds__(256) void k_scan(
        const int* __restrict__ cnt, int* __restrict__ rowstart,
        int* __restrict__ cursor) {
    __shared__ int partial[256];
    int t = threadIdx.x;
    int loc[8];
    int run = 0;
#pragma unroll
    for (int j = 0; j < 8; j++) {
        int v = cnt[t * 8 + j];
        loc[j] = run; run += v;
    }
    partial[t] = run;
    __syncthreads();
    if (t == 0) {
        int acc = 0;
        for (int i = 0; i < 256; i++) { int v = partial[i]; partial[i] = acc; acc += v; }
        rowstart[2048] = acc;
    }
    __syncthreads();
    int base = partial[t];
#pragma unroll
    for (int j = 0; j < 8; j++) {
        rowstart[t * 8 + j] = base + loc[j];
        cursor[t * 8 + j] = base + loc[j];
    }
}

__global__ __launch_bounds__(256) void k_fill(
        const int* __restrict__ eidx, int* __restrict__ cursor,
        int* __restrict__ elist) {
    int e = blockIdx.x * 256 + threadIdx.x;
    if (e >= NEDGES) return;
    int src = eidx[e];
    int pos = atomicAdd(&cursor[src], 1);
    elist[pos] = e;
}

// ---------------------------------------------------------------------------
// Gather + fused abnorm (R13 version): NH threads; adjacent lane pairs split
// a node's edge list; software-pipelined edge loop (prefetch next elist/eidx).
__global__ __launch_bounds__(256) void k_gather_ab(
        const __hip_bfloat16* __restrict__ ea /* [E][384], col=h*3+comp */,
        const int* __restrict__ eidx,
        const int* __restrict__ rowstart, const int* __restrict__ elist,
        const __hip_bfloat16* __restrict__ Yb, const float* __restrict__ q,
        __hip_bfloat16* __restrict__ Tb) {
    int gid = blockIdx.x * 256 + threadIdx.x;   // NH threads
    int n = gid >> 7;
    int t7 = gid & 127;
    int hp = t7 >> 1;          // h-pair index 0..63
    int half = t7 & 1;         // which half of the edge list / which column
    int h0 = hp << 1;
    int beg = rowstart[n], end = rowstart[n + 1];
    const unsigned short* Y = (const unsigned short*)Yb;

    // own-node Y (hoisted: overlaps the edge loop)
    int hcol = h0 + half;
    const unsigned short* ypn = Y + (size_t)n * NP + hcol;
    float yd[9];
#pragma unroll
    for (int c = 0; c < 9; c++) yd[c] = b2f(ypn[(size_t)c * H]);

    float acc[9][2];
#pragma unroll
    for (int c = 0; c < 9; c++) { acc[c][0] = 0.f; acc[c][1] = 0.f; }

    int idx = beg + half;
    int e = 0, dst = 0;
    if (idx < end) { e = elist[idx]; dst = eidx[NEDGES + e]; }
    while (idx < end) {
        int nidx = idx + 2;
        int ne = e, ndst = dst;
        if (nidx < end) { ne = elist[nidx]; ndst = eidx[NEDGES + ne]; }
        const unsigned short* eap = (const unsigned short*)ea + (size_t)e * 384 + h0 * 3;
        unsigned u0 = *(const unsigned*)(eap);
        unsigned u1 = *(const unsigned*)(eap + 2);
        unsigned u2 = *(const unsigned*)(eap + 4);
        float w0a = b2f(u0 & 0xffff), w1a = b2f(u0 >> 16);
        float w2a = b2f(u1 & 0xffff), w0b = b2f(u1 >> 16);
        float w1b = b2f(u2 & 0xffff), w2b = b2f(u2 >> 16);
        const unsigned short* yp = Y + (size_t)dst * NP + h0;
        ushort2 y;
        y = *(const ushort2*)(yp + 0 * H); acc[0][0] += w0a * b2f(y.x); acc[0][1] += w0b * b2f(y.y);
        y = *(const ushort2*)(yp + 1 * H); acc[1][0] += w1a * b2f(y.x); acc[1][1] += w1b * b2f(y.y);
        y = *(const ushort2*)(yp + 2 * H); acc[2][0] += w1a * b2f(y.x); acc[2][1] += w1b * b2f(y.y);
        y = *(const ushort2*)(yp + 3 * H); acc[3][0] += w1a * b2f(y.x); acc[3][1] += w1b * b2f(y.y);
#pragma unroll
        for (int c = 4; c < 9; c++) {
            y = *(const ushort2*)(yp + c * H);
            acc[c][0] += w2a * b2f(y.x); acc[c][1] += w2b * b2f(y.y);
        }
        idx = nidx; e = ne; dst = ndst;
    }
    // combine the two halves (lanes differ only in bit 0)
#pragma unroll
    for (int c = 0; c < 9; c++) {
        acc[c][0] += __shfl_xor(acc[c][0], 1);
        acc[c][1] += __shfl_xor(acc[c][1], 1);
    }
    // fused abnorm: this lane handles column h0+half
    float scale = 1.f + 0.1f * q[n];
    float md[9];
#pragma unroll
    for (int c = 0; c < 9; c++) md[c] = acc[c][half];
    float m[9], yf[9];
    build_full(md, m);
    build_full(yd, yf);
    float ab[9];
#pragma unroll
    for (int ii = 0; ii < 3; ii++)
#pragma unroll
        for (int jj = 0; jj < 3; jj++) {
            float s = 0.f;
#pragma unroll
            for (int kk = 0; kk < 3; kk++)
                s += m[ii * 3 + kk] * yf[kk * 3 + jj] + yf[ii * 3 + kk] * m[kk * 3 + jj];
            ab[ii * 3 + jj] = s;
        }
    float nrm = 0.f;
#pragma unroll
    for (int j = 0; j < 9; j++) { ab[j] *= scale; nrm += ab[j] * ab[j]; }
    float inv = 1.f / (nrm + 1.f);
    float tr3 = (ab[0] + ab[4] + ab[8]) * (1.f / 3.f);
    unsigned short* T = (unsigned short*)Tb + (size_t)n * NP + hcol;
    T[0 * H] = f2b(tr3 * inv);
    T[1 * H] = f2b(0.5f * (ab[1] - ab[3]) * inv);
    T[2 * H] = f2b(0.5f * (ab[2] - ab[6]) * inv);
    T[3 * H] = f2b(0.5f * (ab[5] - ab[7]) * inv);
    T[4 * H] = f2b((ab[0] - tr3) * inv);
    T[5 * H] = f2b(0.5f * (ab[1] + ab[3]) * inv);
    T[6 * H] = f2b(0.5f * (ab[2] + ab[6]) * inv);
    T[7 * H] = f2b((ab[4] - tr3) * inv);
    T[8 * H] = f2b(0.5f * (ab[5] + ab[7]) * inv);
}

// ---------------------------------------------------------------------------
// Final: Xout = Xn + dX + (1+0.1q)*dX@dX.  dX interleaved bf16 [n][9][H].
// PREP: also normalize+decompose Xout into Xn (fp32) and Db (bf16) for next layer.
template <bool PREP>
__global__ __launch_bounds__(256) void k_final(
        const __hip_bfloat16* __restrict__ dXb, const float* __restrict__ Xn,
        const float* __restrict__ q, float* __restrict__ Xout,
        float* __restrict__ XnW, __hip_bfloat16* __restrict__ Db) {
    int i = blockIdx.x * 256 + threadIdx.x;
    if (i >= NH) return;
    const unsigned short* dX = (const unsigned short*)dXb + (size_t)(i >> 7) * NP + (i & 127);
    float dd[9];
#pragma unroll
    for (int c = 0; c < 9; c++) dd[c] = b2f(dX[(size_t)c * H]);
    float dx[9];
    build_full(dd, dx);
    float scale = 1.f + 0.1f * q[i >> 7];
    float out[9];
#pragma unroll
    for (int ii = 0; ii < 3; ii++)
#pragma unroll
        for (int jj = 0; jj < 3; jj++) {
            float s = 0.f;
#pragma unroll
            for (int kk = 0; kk < 3; kk++)
                s += dx[ii * 3 + kk] * dx[kk * 3 + jj];
            out[ii * 3 + jj] = Xn[(size_t)i * 9 + ii * 3 + jj] + dx[ii * 3 + jj] + scale * s;
        }
#pragma unroll
    for (int j = 0; j < 9; j++) Xout[(size_t)i * 9 + j] = out[j];
    if (PREP) {
        float ss = 0.f;
#pragma unroll
        for (int j = 0; j < 9; j++) ss += out[j] * out[j];
        float inv = 1.f / (ss + 1.f);
        float v[9];
#pragma unroll
        for (int j = 0; j < 9; j++) { v[j] = out[j] * inv; XnW[(size_t)i * 9 + j] = v[j]; }
        float i0 = (v[0] + v[4] + v[8]) * (1.f / 3.f);
        unsigned short* D = (unsigned short*)Db + (size_t)(i >> 7) * NP + (i & 127);
        D[0 * H] = f2b(i0);
        D[1 * H] = f2b(0.5f * (v[1] - v[3]));
        D[2 * H] = f2b(0.5f * (v[2] - v[6]));
        D[3 * H] = f2b(0.5f * (v[5] - v[7]));
        D[4 * H] = f2b(v[0] - i0);
        D[5 * H] = f2b(0.5f * (v[1] + v[3]));
        D[6 * H] = f2b(0.5f * (v[2] + v[6]));
        D[7 * H] = f2b(v[4] - i0);
        D[8 * H] = f2b(0.5f * (v[5] + v[7]));
    }
}

// ---------------------------------------------------------------------------
extern "C" void kernel_launch(void* const* d_in, const int* in_sizes, int n_in,
                              void* d_out, int out_size, void* d_ws, size_t ws_size,
                              hipStream_t stream) {
    const float* X          = (const float*)d_in[0];
    const float* edge_attr  = (const float*)d_in[1];
    const float* edge_weight= (const float*)d_in[2];
    const float* q          = (const float*)d_in[3];
    const float* Ws1        = (const float*)d_in[4];
    const float* bs1        = (const float*)d_in[5];
    const float* Ws2        = (const float*)d_in[6];
    const float* bs2        = (const float*)d_in[7];
    const float* Ws3        = (const float*)d_in[8];
    const float* bs3        = (const float*)d_in[9];
    const float* Wt         = (const float*)d_in[10];
    const int*   eidx       = (const int*)d_in[11];
    float* Xout = (float*)d_out;

    char* p = (char*)d_ws;
    auto alloc = [&](size_t bytes) -> char* {
        char* r = p; p += (bytes + 255) & ~(size_t)255; return r;
    };
    size_t nodeBytes = (size_t)NH * 9 * sizeof(float);
    float* Xn   = (float*)alloc(nodeBytes);
    __hip_bfloat16* Db = (__hip_bfloat16*)alloc((size_t)NH * 9 * 2);  // D / T planes
    __hip_bfloat16* Yb = (__hip_bfloat16*)alloc((size_t)NH * 9 * 2);  // Y, then dX
    __hip_bfloat16* eaB = (__hip_bfloat16*)alloc((size_t)C0 * 2);
    __hip_bfloat16* W1b = (__hip_bfloat16*)alloc((size_t)C1 * 2);
    __hip_bfloat16* W2b = (__hip_bfloat16*)alloc((size_t)C2 * 2);
    __hip_bfloat16* W3b = (__hip_bfloat16*)alloc((size_t)C3 * 2);
    __hip_bfloat16* Wtb = (__hip_bfloat16*)alloc((size_t)C4 * 2);
    __hip_bfloat16* ea3g = (__hip_bfloat16*)alloc((size_t)2 * NEDGES * 384 * 2);
    int* cnt      = (int*)alloc(2048 * 4);
    int* rowstart = (int*)alloc(2049 * 4);
    int* cursor   = (int*)alloc(2048 * 4);
    int* elist    = (int*)alloc(NEDGES * 4);

    // one-time bf16 casts + cnt zeroing + node prep (fused)
    k_cast_all<<<(CAST_TOTAL + 255) / 256, 256, 0, stream>>>(
        edge_attr, Ws1, Ws2, Ws3, Wt, eaB, W1b, W2b, W3b, Wtb, cnt,
        X, Xn, Db);

    // CSR once (edge_index static across layers)
    k_hist<<<NEDGES / 256, 256, 0, stream>>>(eidx, cnt);
    k_scan<<<1, 256, 0, stream>>>(cnt, rowstart, cursor);
    k_fill<<<NEDGES / 256, 256, 0, stream>>>(eidx, cursor, elist);

    // edge MLP for BOTH layers in one launch (independent of X)
    k_mlp_fused<<<dim3(NEDGES / ETILE, 1, 2), 512, 0, stream>>>(
        eaB, W1b, W2b, W3b, bs1, bs2, bs3, edge_weight, ea3g);

    for (int l = 0; l < 2; l++) {
        const __hip_bfloat16* Wtl = Wtb + (size_t)l * 6 * H * H;
        const __hip_bfloat16* ea3 = ea3g + (size_t)l * NEDGES * 384;

        // Y = chan_mix(decomposed Xn) -> bf16 interleaved planes
        k_mix<<<dim3(NATOMS / 128, 2, 9), 256, 0, stream>>>(Db, Wtl, Yb, 0);
        // gather + fused abnorm -> Tb (reuses Db)
        k_gather_ab<<<NH / 256, 256, 0, stream>>>(
            ea3, eidx, rowstart, elist, Yb, q, Db);
        // dX = chan_mix(T) -> bf16 interleaved planes (reuses Yb)
        k_mix<<<dim3(NATOMS / 128, 2, 9), 256, 0, stream>>>(Db, Wtl, Yb, 3);
        // final (+ fused node-prep for next layer)
        if (l == 0)
            k_final<true><<<NH / 256, 256, 0, stream>>>(Yb, Xn, q, Xout, Xn, Db);
        else
            k_final<false><<<NH / 256, 256, 0, stream>>>(Yb, Xn, q, Xout, nullptr, nullptr);
    }
}

// Round 16
// 151.531 us; speedup vs baseline: 1.1231x; 1.0331x over previous
//
#include <hip/hip_runtime.h>
#include <hip/hip_bf16.h>
#include <math.h>

#define H 128
#define R 32
#define NATOMS 2048
#define NEDGES 32768
#define NH (NATOMS * H)          // 262144 (n,h) pairs
#define NP 1152                  // 9*H: node-plane row stride (interleaved [n][9][H])
#define CUTOFF_F 4.5f
#define PI_OVER_CUTOFF 0.6981317007977318f

typedef __bf16 bf16x8 __attribute__((ext_vector_type(8)));
typedef float f32x4 __attribute__((ext_vector_type(4)));
typedef short short8 __attribute__((ext_vector_type(8)));
typedef unsigned short u16x4 __attribute__((ext_vector_type(4)));

// lgkm-only barrier: LDS visible, global loads stay in flight across it.
#define BAR_LGKM() do { \
    asm volatile("s_waitcnt lgkmcnt(0)" ::: "memory"); \
    __builtin_amdgcn_s_barrier(); \
    asm volatile("" ::: "memory"); \
} while (0)

// ---------------------------------------------------------------------------
// v_rcp_f32 (1 instr, ~1ulp) instead of IEEE divide (~10 instr) — bf16-safe.
__device__ __forceinline__ float rcp_f(float x) {
    return __builtin_amdgcn_rcpf(x);
}
__device__ __forceinline__ float silu_f(float x) {
    return x * rcp_f(1.f + __expf(-x));
}
__device__ __forceinline__ float b2f(unsigned short u) {
    return __uint_as_float(((unsigned)u) << 16);
}
__device__ __forceinline__ unsigned short f2b(float f) {
    __hip_bfloat16 h = __float2bfloat16(f);
    return __builtin_bit_cast(unsigned short, h);
}

// Build full 3x3 from decomposition [i0, a01, a02, a12, s00, s01, s02, s11, s12]
__device__ __forceinline__ void build_full(const float d[9], float m[9]) {
    float i0 = d[0], a01 = d[1], a02 = d[2], a12 = d[3];
    float s00 = d[4], s01 = d[5], s02 = d[6], s11 = d[7], s12 = d[8];
    float s22 = -(s00 + s11);
    m[0] = i0 + s00;  m[1] = a01 + s01;  m[2] = a02 + s02;
    m[3] = s01 - a01; m[4] = i0 + s11;   m[5] = a12 + s12;
    m[6] = s02 - a02; m[7] = s12 - a12;  m[8] = i0 + s22;
}

// ---------------------------------------------------------------------------
// One-shot cast of all fp32 params to bf16 + CSR cnt zeroing + node prep
#define C0 (NEDGES * R)          // edge_attr
#define C1 (2 * H * R)           // Ws1
#define C2 (2 * 2 * H * H)       // Ws2
#define C3 (2 * 3 * H * 2 * H)   // Ws3
#define C4 (2 * 6 * H * H)       // Wt
#define C5 2048                  // cnt zero
#define CAST_TOTAL (C0 + C1 + C2 + C3 + C4 + C5 + NH)
__global__ __launch_bounds__(256) void k_cast_all(
        const float* __restrict__ ea, const float* __restrict__ w1,
        const float* __restrict__ w2, const float* __restrict__ w3,
        const float* __restrict__ wt,
        __hip_bfloat16* __restrict__ oea, __hip_bfloat16* __restrict__ ow1,
        __hip_bfloat16* __restrict__ ow2, __hip_bfloat16* __restrict__ ow3,
        __hip_bfloat16* __restrict__ owt, int* __restrict__ cnt,
        const float* __restrict__ X, float* __restrict__ Xn,
        __hip_bfloat16* __restrict__ Db) {
    int i = blockIdx.x * 256 + threadIdx.x;
    if (i < C0) { oea[i] = __float2bfloat16(ea[i]); return; }
    i -= C0;
    if (i < C1) { ow1[i] = __float2bfloat16(w1[i]); return; }
    i -= C1;
    if (i < C2) { ow2[i] = __float2bfloat16(w2[i]); return; }
    i -= C2;
    if (i < C3) { ow3[i] = __float2bfloat16(w3[i]); return; }
    i -= C3;
    if (i < C4) { owt[i] = __float2bfloat16(wt[i]); return; }
    i -= C4;
    if (i < C5) { cnt[i] = 0; return; }
    i -= C5;
    if (i < NH) {
        const float* x = X + (size_t)i * 9;
        float v[9];
        float ss = 0.f;
#pragma unroll
        for (int j = 0; j < 9; j++) { v[j] = x[j]; ss += v[j] * v[j]; }
        float inv = rcp_f(ss + 1.f);
#pragma unroll
        for (int j = 0; j < 9; j++) { v[j] *= inv; Xn[(size_t)i * 9 + j] = v[j]; }
        float i0 = (v[0] + v[4] + v[8]) * (1.f / 3.f);
        unsigned short* D = (unsigned short*)Db + (size_t)(i >> 7) * NP + (i & 127);
        D[0 * H] = f2b(i0);
        D[1 * H] = f2b(0.5f * (v[1] - v[3]));
        D[2 * H] = f2b(0.5f * (v[2] - v[6]));
        D[3 * H] = f2b(0.5f * (v[5] - v[7]));
        D[4 * H] = f2b(v[0] - i0);
        D[5 * H] = f2b(0.5f * (v[1] + v[3]));
        D[6 * H] = f2b(0.5f * (v[2] + v[6]));
        D[7 * H] = f2b(v[4] - i0);
        D[8 * H] = f2b(0.5f * (v[5] + v[7]));
    }
}

// ---------------------------------------------------------------------------
// bf16 MFMA 128x64 tile-GEMM core for the channel mix (K=128), strided A.
// GUARDED variant: only threads with `active` do work; barriers are
// unconditional so it can run inside a 512-thread block with 256 workers.
struct TGm {
    static constexpr int BKm = 64;
    static constexpr int RB  = 128;        // row bytes per K-step
    static constexpr int SWZ = 7;
    static constexpr int NIT = 2;
    static constexpr int ABYTES = 128 * RB;
    static constexpr int BBYTES = 64 * RB;
    static constexpr int AISS = ABYTES / 4096;
    static constexpr int BISS = BBYTES / 4096;
    static constexpr int LDSB = ABYTES + BBYTES;
};

__device__ __forceinline__ void tile_gemm_mix_g(
        const __hip_bfloat16* __restrict__ A, int strideA,
        const __hip_bfloat16* __restrict__ W,
        int m0, int n0, char* lds, f32x4 acc[4][2], bool active) {
    using T = TGm;
    const int t = threadIdx.x;
    const int lane = t & 63;
    const int w = t >> 6;

    auto stage = [&](int b, int it) {
        const int k0 = it * T::BKm;
        char* As = lds + b * T::LDSB;
        char* Bs = As + T::ABYTES;
#pragma unroll
        for (int i = 0; i < T::AISS; i++) {
            int base = (w * T::AISS + i) * 1024;
            int lin = base + lane * 16;
            int row = lin / T::RB;
            int slot = (lin % T::RB) >> 4;
            int sl = slot ^ (row & T::SWZ);
            const char* src = (const char*)(A + (size_t)(m0 + row) * strideA + k0) + sl * 16;
            __builtin_amdgcn_global_load_lds(
                (const __attribute__((address_space(1))) void*)src,
                (__attribute__((address_space(3))) void*)(As + base), 16, 0, 0);
        }
#pragma unroll
        for (int i = 0; i < T::BISS; i++) {
            int base = (w * T::BISS + i) * 1024;
            int lin = base + lane * 16;
            int row = lin / T::RB;
            int slot = (lin % T::RB) >> 4;
            int sl = slot ^ (row & T::SWZ);
            const char* src = (const char*)(W + (size_t)(n0 + row) * H + k0) + sl * 16;
            __builtin_amdgcn_global_load_lds(
                (const __attribute__((address_space(1))) void*)src,
                (__attribute__((address_space(3))) void*)(Bs + base), 16, 0, 0);
        }
    };

    auto compute = [&](int b) {
        const char* As = lds + b * T::LDSB;
        const char* Bs = As + T::ABYTES;
        const int wm = (w & 1) * 64;
        const int wn = (w >> 1) * 32;
        const int rA = wm + (lane & 15);
        const int rB = wn + (lane & 15);
        const int c = lane >> 4;
#pragma unroll
        for (int kk = 0; kk < T::BKm / 32; kk++) {
            bf16x8 av[4], bv[2];
#pragma unroll
            for (int mf = 0; mf < 4; mf++) {
                int row = rA + mf * 16;
                int sp = (kk * 4 + c) ^ (row & T::SWZ);
                av[mf] = __builtin_bit_cast(bf16x8,
                    *(const short8*)(As + row * T::RB + sp * 16));
            }
#pragma unroll
            for (int nf = 0; nf < 2; nf++) {
                int row = rB + nf * 16;
                int sp = (kk * 4 + c) ^ (row & T::SWZ);
                bv[nf] = __builtin_bit_cast(bf16x8,
                    *(const short8*)(Bs + row * T::RB + sp * 16));
            }
#pragma unroll
            for (int mf = 0; mf < 4; mf++)
#pragma unroll
                for (int nf = 0; nf < 2; nf++)
                    acc[mf][nf] = __builtin_amdgcn_mfma_f32_16x16x32_bf16(
                        av[mf], bv[nf], acc[mf][nf], 0, 0, 0);
        }
    };

    if (active) stage(0, 0);
    asm volatile("s_waitcnt vmcnt(0)" ::: "memory");
    __syncthreads();
    for (int it = 0; it < T::NIT; it++) {
        int b = it & 1;
        if (active && it + 1 < T::NIT) stage(b ^ 1, it + 1);
        if (active) compute(b);
        asm volatile("s_waitcnt vmcnt(0)" ::: "memory");
        __syncthreads();
    }
}

// Standalone channel-mix (256 threads): 9 planes [n][9][H] @ Wt-part.
__global__ __launch_bounds__(256) void k_mix(
        const __hip_bfloat16* __restrict__ Db, const __hip_bfloat16* __restrict__ Wtb,
        __hip_bfloat16* __restrict__ Outp, int partOff) {
    __shared__ char lds[2 * TGm::LDSB];
    int c = blockIdx.z;
    int part = (c == 0) ? 0 : ((c < 4) ? 1 : 2);
    const __hip_bfloat16* A = Db + (size_t)c * H;
    const __hip_bfloat16* W = Wtb + (size_t)(partOff + part) * H * H;
    unsigned short* Out = (unsigned short*)Outp + (size_t)c * H;
    const int lane = threadIdx.x & 63;
    const int w = threadIdx.x >> 6;
    const int wm = (w & 1) * 64, wn = (w >> 1) * 32;
    const int m0 = blockIdx.x * 128, n0 = blockIdx.y * 64;
    f32x4 acc[4][2] = {};
    tile_gemm_mix_g(A, NP, W, m0, n0, lds, acc, true);
#pragma unroll
    for (int mf = 0; mf < 4; mf++)
#pragma unroll
        for (int r = 0; r < 4; r++) {
            int row = m0 + wm + mf * 16 + (lane >> 4) * 4 + r;
#pragma unroll
            for (int nf = 0; nf < 2; nf++) {
                int col = n0 + wn + nf * 16 + (lane & 15);
                Out[(size_t)row * NP + col] = f2b(acc[mf][nf][r]);
            }
        }
}

// ---------------------------------------------------------------------------
// FAT kernel: blocks [0, MIXBLOCKS) do the layer-0 Y channel-mix (256 active
// threads of 512); blocks [MIXBLOCKS, +1024) do the fused 3-stage edge MLP
// for both layers. The two roles are independent (both consume only
// k_cast_all outputs), so the mix hides in the MLP's idle issue slots.
#define ETILE 64
#define PAD0 40     // sEA row stride (elements)
#define PAD1 136    // act1 row stride
#define PAD2 264    // act2 row stride
#define SA2_B (ETILE * PAD2 * 2)   // 33792 bytes: act2 region (base)
#define SA1_B (ETILE * PAD1 * 2)   // 17408 bytes: act1 (at base, inside act2)
#define SEA_OFF SA1_B              // sEA right after act1 (inside act2 region)
#define MIXBLOCKS 288              // 16 m-tiles x 2 n-tiles x 9 planes
#define FAT_LDS (2 * TGm::LDSB + 256)   // 49408: union of mix(48K) and mlp(34K+ew)

__global__ __launch_bounds__(512, 3) void k_fat(
        const __hip_bfloat16* __restrict__ eaB,
        const __hip_bfloat16* __restrict__ W1b, const __hip_bfloat16* __restrict__ W2b,
        const __hip_bfloat16* __restrict__ W3b,
        const float* __restrict__ bs1, const float* __restrict__ bs2,
        const float* __restrict__ bs3, const float* __restrict__ ew,
        __hip_bfloat16* __restrict__ ea3g,
        const __hip_bfloat16* __restrict__ Db, const __hip_bfloat16* __restrict__ Wtb,
        __hip_bfloat16* __restrict__ Yb) {
    __shared__ char smem[FAT_LDS];
    int bid = blockIdx.x;

    if (bid < MIXBLOCKS) {
        // ---- mix role: layer-0 Y = chan_mix(Db) ----
        int c = bid / 32;
        int rem = bid & 31;
        int m0 = (rem & 15) * 128;
        int n0 = (rem >> 4) * 64;
        int part = (c == 0) ? 0 : ((c < 4) ? 1 : 2);
        const __hip_bfloat16* A = Db + (size_t)c * H;
        const __hip_bfloat16* W = Wtb + (size_t)part * H * H;
        unsigned short* Out = (unsigned short*)Yb + (size_t)c * H;
        bool active = threadIdx.x < 256;
        f32x4 acc[4][2] = {};
        tile_gemm_mix_g(A, NP, W, m0, n0, smem, acc, active);
        if (active) {
            const int lane = threadIdx.x & 63;
            const int w = threadIdx.x >> 6;
            const int wm = (w & 1) * 64, wn = (w >> 1) * 32;
#pragma unroll
            for (int mf = 0; mf < 4; mf++)
#pragma unroll
                for (int r = 0; r < 4; r++) {
                    int row = m0 + wm + mf * 16 + (lane >> 4) * 4 + r;
#pragma unroll
                    for (int nf = 0; nf < 2; nf++) {
                        int col = n0 + wn + nf * 16 + (lane & 15);
                        Out[(size_t)row * NP + col] = f2b(acc[mf][nf][r]);
                    }
                }
        }
        return;
    }
    bid -= MIXBLOCKS;

    // ---- mlp role ----
    const int l = bid >> 9;
    const unsigned short* W1 = (const unsigned short*)W1b + (size_t)l * (H * R);
    const unsigned short* W2 = (const unsigned short*)W2b + (size_t)l * (2 * H * H);
    const unsigned short* W3 = (const unsigned short*)W3b + (size_t)l * (3 * H * 2 * H);
    const float* b1 = bs1 + (size_t)l * H;
    const float* b2 = bs2 + (size_t)l * 2 * H;
    const float* b3 = bs3 + (size_t)l * 3 * H;
    unsigned short* outp = (unsigned short*)ea3g + (size_t)l * NEDGES * 384;
    const int e0 = (bid & 511) * ETILE;

    unsigned short* sA2 = (unsigned short*)smem;               // [64][PAD2]
    unsigned short* sA1 = (unsigned short*)smem;               // [64][PAD1] at base
    unsigned short* sEA = (unsigned short*)(smem + SEA_OFF);   // [64][PAD0]
    float* sEW = (float*)(smem + SA2_B);                       // ew cache

    const int t = threadIdx.x;
    const int lane = t & 63;
    const int w = t >> 6;        // 0..7
    const int q = lane >> 4;     // k-chunk index (0..3)
    const int li = lane & 15;

    const int cbase1 = w * 16;
    const int cbase2 = w * 32;
    const int cbase3 = w * 48;

    // Early global issues (independent of LDS): W1 fragment + bias1.
    bf16x8 av1 = __builtin_bit_cast(bf16x8,
        *(const short8*)(W1 + (size_t)(cbase1 + li) * R + q * 8));
    f32x4 bb1 = *(const f32x4*)&b1[cbase1 + q * 4];

    // stage edge_attr tile [64][32] + ew tile
    {
        if (t < 256) {
            int row = t >> 2, c8 = t & 3;
            *(uint4*)(sEA + row * PAD0 + c8 * 8) =
                *(const uint4*)((const unsigned short*)eaB + (size_t)(e0 + row) * R + c8 * 8);
        }
        if (t < ETILE) sEW[t] = ew[e0 + t];
    }
    BAR_LGKM();                                       // (1) sEA/sEW visible

    // ---- GEMM1: W1[128,32] @ ea^T -> act1^T ----
    f32x4 acc1[4] = {};
#pragma unroll
    for (int ef = 0; ef < 4; ef++) {
        bf16x8 bv = __builtin_bit_cast(bf16x8,
            *(const short8*)(sEA + (ef * 16 + li) * PAD0 + q * 8));
        acc1[ef] = __builtin_amdgcn_mfma_f32_16x16x32_bf16(av1, bv, acc1[ef], 0, 0, 0);
    }

    // Issue ALL GEMM2 weights now — they fly across GEMM1 epilogue + barrier.
    bf16x8 a2[4][2];
#pragma unroll
    for (int ks = 0; ks < 4; ks++)
#pragma unroll
        for (int mf = 0; mf < 2; mf++)
            a2[ks][mf] = __builtin_bit_cast(bf16x8,
                *(const short8*)(W2 + (size_t)(cbase2 + mf * 16 + li) * H
                                 + ks * 32 + q * 8));
    f32x4 bb2[2];
#pragma unroll
    for (int mf = 0; mf < 2; mf++)
        bb2[mf] = *(const f32x4*)&b2[cbase2 + mf * 16 + q * 4];

    // GEMM1 epilogue (writes act1 region [0..SA1_B), disjoint from sEA)
#pragma unroll
    for (int ef = 0; ef < 4; ef++) {
        u16x4 o;
#pragma unroll
        for (int r = 0; r < 4; r++) o[r] = f2b(silu_f(acc1[ef][r] + bb1[r]));
        *(u16x4*)(sA1 + (ef * 16 + li) * PAD1 + cbase1 + q * 4) = o;
    }
    BAR_LGKM();                                       // (2) act1 visible

    // ---- GEMM2: W2[256,128] @ act1^T -> act2^T (weights all in regs) ----
    f32x4 acc2[2][4] = {};
#pragma unroll
    for (int ks = 0; ks < 4; ks++) {
        bf16x8 bv[4];
#pragma unroll
        for (int ef = 0; ef < 4; ef++)
            bv[ef] = __builtin_bit_cast(bf16x8,
                *(const short8*)(sA1 + (ef * 16 + li) * PAD1 + ks * 32 + q * 8));
#pragma unroll
        for (int mf = 0; mf < 2; mf++)
#pragma unroll
            for (int ef = 0; ef < 4; ef++)
                acc2[mf][ef] = __builtin_amdgcn_mfma_f32_16x16x32_bf16(
                    a2[ks][mf], bv[ef], acc2[mf][ef], 0, 0, 0);
    }

    // Issue GEMM3's first 3 k-slice weights — fly across epilogue + 2 barriers.
    bf16x8 a3[3][3];   // [ks%3][mf]
#pragma unroll
    for (int pk = 0; pk < 3; pk++)
#pragma unroll
        for (int mf = 0; mf < 3; mf++)
            a3[pk][mf] = __builtin_bit_cast(bf16x8,
                *(const short8*)(W3 + (size_t)(cbase3 + mf * 16 + li) * (2 * H)
                                 + pk * 32 + q * 8));

    BAR_LGKM();   // (3) all act1/sEA reads done; safe to overwrite with act2
#pragma unroll
    for (int mf = 0; mf < 2; mf++)
#pragma unroll
        for (int ef = 0; ef < 4; ef++) {
            u16x4 o;
#pragma unroll
            for (int r = 0; r < 4; r++)
                o[r] = f2b(silu_f(acc2[mf][ef][r] + bb2[mf][r]));
            *(u16x4*)(sA2 + (ef * 16 + li) * PAD2 + cbase2 + mf * 16 + q * 4) = o;
        }
    BAR_LGKM();                                       // (4) act2 visible

    // ---- GEMM3: W3[384,256] @ act2^T, 3-deep rotating weight prefetch ----
    f32x4 acc3[3][4] = {};
#pragma unroll
    for (int ks = 0; ks < 8; ks++) {
        const int slot = ks % 3;
        bf16x8 bv[4];
#pragma unroll
        for (int ef = 0; ef < 4; ef++)
            bv[ef] = __builtin_bit_cast(bf16x8,
                *(const short8*)(sA2 + (ef * 16 + li) * PAD2 + ks * 32 + q * 8));
#pragma unroll
        for (int mf = 0; mf < 3; mf++)
#pragma unroll
            for (int ef = 0; ef < 4; ef++)
                acc3[mf][ef] = __builtin_amdgcn_mfma_f32_16x16x32_bf16(
                    a3[slot][mf], bv[ef], acc3[mf][ef], 0, 0, 0);
        if (ks + 3 < 8) {   // reload this slot for iteration ks+3
#pragma unroll
            for (int mf = 0; mf < 3; mf++)
                a3[slot][mf] = __builtin_bit_cast(bf16x8,
                    *(const short8*)(W3 + (size_t)(cbase3 + mf * 16 + li) * (2 * H)
                                     + (ks + 3) * 32 + q * 8));
        }
    }
    f32x4 bb3[3];
#pragma unroll
    for (int mf = 0; mf < 3; mf++)
        bb3[mf] = *(const f32x4*)&b3[cbase3 + mf * 16 + q * 4];
#pragma unroll
    for (int ef = 0; ef < 4; ef++) {
        int edge = ef * 16 + li;
        float wv = sEW[edge];
        float cs = (wv < CUTOFF_F) ? 0.5f * (__cosf(wv * PI_OVER_CUTOFF) + 1.f) : 0.f;
#pragma unroll
        for (int mf = 0; mf < 3; mf++) {
            u16x4 o;
#pragma unroll
            for (int r = 0; r < 4; r++)
                o[r] = f2b(silu_f(acc3[mf][ef][r] + bb3[mf][r]) * cs);
            *(u16x4*)(outp + (size_t)(e0 + edge) * 384 + cbase3 + mf * 16 + q * 4) = o;
        }
    }
}

// ---------------------------------------------------------------------------
// CSR build (once; edge_index is static across layers)
__global__ __launch_bounds__(256) void k_hist(
        const int* __restrict__ eidx, int* __restrict__ cnt) {
    int e = blockIdx.x * 256 + threadIdx.x;
    if (e < NEDGES) atomicAdd(&cnt[eidx[e]], 1);
}

__global__ __launch_bounds__(256) void k_scan(
        const int* __restrict__ cnt, int* __restrict__ rowstart,
        int* __restrict__ cursor) {
    __shared__ int partial[256];
    int t = threadIdx.x;
    int loc[8];
    int run = 0;
#pragma unroll
    for (int j = 0; j < 8; j++) {
        int v = cnt[t * 8 + j];
        loc[j] = run; run += v;
    }
    partial[t] = run;
    __syncthreads();
    if (t == 0) {
        int acc = 0;
        for (int i = 0; i < 256; i++) { int v = partial[i]; partial[i] = acc; acc += v; }
        rowstart[2048] = acc;
    }
    __syncthreads();
    int base = partial[t];
#pragma unroll
    for (int j = 0; j < 8; j++) {
        rowstart[t * 8 + j] = base + loc[j];
        cursor[t * 8 + j] = base + loc[j];
    }
}

__global__ __launch_bounds__(256) void k_fill(
        const int* __restrict__ eidx, int* __restrict__ cursor,
        int* __restrict__ elist) {
    int e = blockIdx.x * 256 + threadIdx.x;
    if (e >= NEDGES) return;
    int src = eidx[e];
    int pos = atomicAdd(&cursor[src], 1);
    elist[pos] = e;
}

// ---------------------------------------------------------------------------
// Gather + fused abnorm: NH threads; adjacent lane pairs split a node's
// edge list; software-pipelined edge loop (prefetch next elist/eidx).
__global__ __launch_bounds__(256) void k_gather_ab(
        const __hip_bfloat16* __restrict__ ea /* [E][384], col=h*3+comp */,
        const int* __restrict__ eidx,
        const int* __restrict__ rowstart, const int* __restrict__ elist,
        const __hip_bfloat16* __restrict__ Yb, const float* __restrict__ q,
        __hip_bfloat16* __restrict__ Tb) {
    int gid = blockIdx.x * 256 + threadIdx.x;   // NH threads
    int n = gid >> 7;
    int t7 = gid & 127;
    int hp = t7 >> 1;          // h-pair index 0..63
    int half = t7 & 1;         // which half of the edge list / which column
    int h0 = hp << 1;
    int beg = rowstart[n], end = rowstart[n + 1];
    const unsigned short* Y = (const unsigned short*)Yb;

    // own-node Y (hoisted: overlaps the edge loop)
    int hcol = h0 + half;
    const unsigned short* ypn = Y + (size_t)n * NP + hcol;
    float yd[9];
#pragma unroll
    for (int c = 0; c < 9; c++) yd[c] = b2f(ypn[(size_t)c * H]);

    float acc[9][2];
#pragma unroll
    for (int c = 0; c < 9; c++) { acc[c][0] = 0.f; acc[c][1] = 0.f; }

    int idx = beg + half;
    int e = 0, dst = 0;
    if (idx < end) { e = elist[idx]; dst = eidx[NEDGES + e]; }
    while (idx < end) {
        int nidx = idx + 2;
        int ne = e, ndst = dst;
        if (nidx < end) { ne = elist[nidx]; ndst = eidx[NEDGES + ne]; }
        const unsigned short* eap = (const unsigned short*)ea + (size_t)e * 384 + h0 * 3;
        unsigned u0 = *(const unsigned*)(eap);
        unsigned u1 = *(const unsigned*)(eap + 2);
        unsigned u2 = *(const unsigned*)(eap + 4);
        float w0a = b2f(u0 & 0xffff), w1a = b2f(u0 >> 16);
        float w2a = b2f(u1 & 0xffff), w0b = b2f(u1 >> 16);
        float w1b = b2f(u2 & 0xffff), w2b = b2f(u2 >> 16);
        const unsigned short* yp = Y + (size_t)dst * NP + h0;
        ushort2 y;
        y = *(const ushort2*)(yp + 0 * H); acc[0][0] += w0a * b2f(y.x); acc[0][1] += w0b * b2f(y.y);
        y = *(const ushort2*)(yp + 1 * H); acc[1][0] += w1a * b2f(y.x); acc[1][1] += w1b * b2f(y.y);
        y = *(const ushort2*)(yp + 2 * H); acc[2][0] += w1a * b2f(y.x); acc[2][1] += w1b * b2f(y.y);
        y = *(const ushort2*)(yp + 3 * H); acc[3][0] += w1a * b2f(y.x); acc[3][1] += w1b * b2f(y.y);
#pragma unroll
        for (int c = 4; c < 9; c++) {
            y = *(const ushort2*)(yp + c * H);
            acc[c][0] += w2a * b2f(y.x); acc[c][1] += w2b * b2f(y.y);
        }
        idx = nidx; e = ne; dst = ndst;
    }
    // combine the two halves (lanes differ only in bit 0)
#pragma unroll
    for (int c = 0; c < 9; c++) {
        acc[c][0] += __shfl_xor(acc[c][0], 1);
        acc[c][1] += __shfl_xor(acc[c][1], 1);
    }
    // fused abnorm: this lane handles column h0+half
    float scale = 1.f + 0.1f * q[n];
    float md[9];
#pragma unroll
    for (int c = 0; c < 9; c++) md[c] = acc[c][half];
    float m[9], yf[9];
    build_full(md, m);
    build_full(yd, yf);
    float ab[9];
#pragma unroll
    for (int ii = 0; ii < 3; ii++)
#pragma unroll
        for (int jj = 0; jj < 3; jj++) {
            float s = 0.f;
#pragma unroll
            for (int kk = 0; kk < 3; kk++)
                s += m[ii * 3 + kk] * yf[kk * 3 + jj] + yf[ii * 3 + kk] * m[kk * 3 + jj];
            ab[ii * 3 + jj] = s;
        }
    float nrm = 0.f;
#pragma unroll
    for (int j = 0; j < 9; j++) { ab[j] *= scale; nrm += ab[j] * ab[j]; }
    float inv = rcp_f(nrm + 1.f);
    float tr3 = (ab[0] + ab[4] + ab[8]) * (1.f / 3.f);
    unsigned short* T = (unsigned short*)Tb + (size_t)n * NP + hcol;
    T[0 * H] = f2b(tr3 * inv);
    T[1 * H] = f2b(0.5f * (ab[1] - ab[3]) * inv);
    T[2 * H] = f2b(0.5f * (ab[2] - ab[6]) * inv);
    T[3 * H] = f2b(0.5f * (ab[5] - ab[7]) * inv);
    T[4 * H] = f2b((ab[0] - tr3) * inv);
    T[5 * H] = f2b(0.5f * (ab[1] + ab[3]) * inv);
    T[6 * H] = f2b(0.5f * (ab[2] + ab[6]) * inv);
    T[7 * H] = f2b((ab[4] - tr3) * inv);
    T[8 * H] = f2b(0.5f * (ab[5] + ab[7]) * inv);
}

// ---------------------------------------------------------------------------
// Final: Xout = Xn + dX + (1+0.1q)*dX@dX.  dX interleaved bf16 [n][9][H].
// PREP: also normalize+decompose Xout into Xn (fp32) and Db (bf16) for next layer.
template <bool PREP>
__global__ __launch_bounds__(256) void k_final(
        const __hip_bfloat16* __restrict__ dXb, const float* __restrict__ Xn,
        const float* __restrict__ q, float* __restrict__ Xout,
        float* __restrict__ XnW, __hip_bfloat16* __restrict__ Db) {
    int i = blockIdx.x * 256 + threadIdx.x;
    if (i >= NH) return;
    const unsigned short* dX = (const unsigned short*)dXb + (size_t)(i >> 7) * NP + (i & 127);
    float dd[9];
#pragma unroll
    for (int c = 0; c < 9; c++) dd[c] = b2f(dX[(size_t)c * H]);
    float dx[9];
    build_full(dd, dx);
    float scale = 1.f + 0.1f * q[i >> 7];
    float out[9];
#pragma unroll
    for (int ii = 0; ii < 3; ii++)
#pragma unroll
        for (int jj = 0; jj < 3; jj++) {
            float s = 0.f;
#pragma unroll
            for (int kk = 0; kk < 3; kk++)
                s += dx[ii * 3 + kk] * dx[kk * 3 + jj];
            out[ii * 3 + jj] = Xn[(size_t)i * 9 + ii * 3 + jj] + dx[ii * 3 + jj] + scale * s;
        }
#pragma unroll
    for (int j = 0; j < 9; j++) Xout[(size_t)i * 9 + j] = out[j];
    if (PREP) {
        float ss = 0.f;
#pragma unroll
        for (int j = 0; j < 9; j++) ss += out[j] * out[j];
        float inv = rcp_f(ss + 1.f);
        float v[9];
#pragma unroll
        for (int j = 0; j < 9; j++) { v[j] = out[j] * inv; XnW[(size_t)i * 9 + j] = v[j]; }
        float i0 = (v[0] + v[4] + v[8]) * (1.f / 3.f);
        unsigned short* D = (unsigned short*)Db + (size_t)(i >> 7) * NP + (i & 127);
        D[0 * H] = f2b(i0);
        D[1 * H] = f2b(0.5f * (v[1] - v[3]));
        D[2 * H] = f2b(0.5f * (v[2] - v[6]));
        D[3 * H] = f2b(0.5f * (v[5] - v[7]));
        D[4 * H] = f2b(v[0] - i0);
        D[5 * H] = f2b(0.5f * (v[1] + v[3]));
        D[6 * H] = f2b(0.5f * (v[2] + v[6]));
        D[7 * H] = f2b(v[4] - i0);
        D[8 * H] = f2b(0.5f * (v[5] + v[7]));
    }
}

// ---------------------------------------------------------------------------
extern "C" void kernel_launch(void* const* d_in, const int* in_sizes, int n_in,
                              void* d_out, int out_size, void* d_ws, size_t ws_size,
                              hipStream_t stream) {
    const float* X          = (const float*)d_in[0];
    const float* edge_attr  = (const float*)d_in[1];
    const float* edge_weight= (const float*)d_in[2];
    const float* q          = (const float*)d_in[3];
    const float* Ws1        = (const float*)d_in[4];
    const float* bs1        = (const float*)d_in[5];
    const float* Ws2        = (const float*)d_in[6];
    const float* bs2        = (const float*)d_in[7];
    const float* Ws3        = (const float*)d_in[8];
    const float* bs3        = (const float*)d_in[9];
    const float* Wt         = (const float*)d_in[10];
    const int*   eidx       = (const int*)d_in[11];
    float* Xout = (float*)d_out;

    char* p = (char*)d_ws;
    auto alloc = [&](size_t bytes) -> char* {
        char* r = p; p += (bytes + 255) & ~(size_t)255; return r;
    };
    size_t nodeBytes = (size_t)NH * 9 * sizeof(float);
    float* Xn   = (float*)alloc(nodeBytes);
    __hip_bfloat16* Db = (__hip_bfloat16*)alloc((size_t)NH * 9 * 2);  // D / T planes
    __hip_bfloat16* Yb = (__hip_bfloat16*)alloc((size_t)NH * 9 * 2);  // Y, then dX
    __hip_bfloat16* eaB = (__hip_bfloat16*)alloc((size_t)C0 * 2);
    __hip_bfloat16* W1b = (__hip_bfloat16*)alloc((size_t)C1 * 2);
    __hip_bfloat16* W2b = (__hip_bfloat16*)alloc((size_t)C2 * 2);
    __hip_bfloat16* W3b = (__hip_bfloat16*)alloc((size_t)C3 * 2);
    __hip_bfloat16* Wtb = (__hip_bfloat16*)alloc((size_t)C4 * 2);
    __hip_bfloat16* ea3g = (__hip_bfloat16*)alloc((size_t)2 * NEDGES * 384 * 2);
    int* cnt      = (int*)alloc(2048 * 4);
    int* rowstart = (int*)alloc(2049 * 4);
    int* cursor   = (int*)alloc(2048 * 4);
    int* elist    = (int*)alloc(NEDGES * 4);

    // one-time bf16 casts + cnt zeroing + node prep (fused)
    k_cast_all<<<(CAST_TOTAL + 255) / 256, 256, 0, stream>>>(
        edge_attr, Ws1, Ws2, Ws3, Wt, eaB, W1b, W2b, W3b, Wtb, cnt,
        X, Xn, Db);

    // CSR once (edge_index static across layers)
    k_hist<<<NEDGES / 256, 256, 0, stream>>>(eidx, cnt);
    k_scan<<<1, 256, 0, stream>>>(cnt, rowstart, cursor);
    k_fill<<<NEDGES / 256, 256, 0, stream>>>(eidx, cursor, elist);

    // FAT: layer-0 Y-mix (288 blocks) + edge MLP both layers (1024 blocks)
    k_fat<<<MIXBLOCKS + 1024, 512, 0, stream>>>(
        eaB, W1b, W2b, W3b, bs1, bs2, bs3, edge_weight, ea3g,
        Db, Wtb, Yb);

    for (int l = 0; l < 2; l++) {
        const __hip_bfloat16* Wtl = Wtb + (size_t)l * 6 * H * H;
        const __hip_bfloat16* ea3 = ea3g + (size_t)l * NEDGES * 384;

        if (l == 1) {
            // Y = chan_mix(decomposed Xn) for layer 1
            k_mix<<<dim3(NATOMS / 128, 2, 9), 256, 0, stream>>>(Db, Wtl, Yb, 0);
        }
        // gather + fused abnorm -> Tb (reuses Db)
        k_gather_ab<<<NH / 256, 256, 0, stream>>>(
            ea3, eidx, rowstart, elist, Yb, q, Db);
        // dX = chan_mix(T) -> bf16 interleaved planes (reuses Yb)
        k_mix<<<dim3(NATOMS / 128, 2, 9), 256, 0, stream>>>(Db, Wtl, Yb, 3);
        // final (+ fused node-prep for next layer)
        if (l == 0)
            k_final<true><<<NH / 256, 256, 0, stream>>>(Yb, Xn, q, Xout, Xn, Db);
        else
            k_final<false><<<NH / 256, 256, 0, stream>>>(Yb, Xn, q, Xout, nullptr, nullptr);
    }
}

// Round 17
// 151.456 us; speedup vs baseline: 1.1236x; 1.0005x over previous
//
#include <hip/hip_runtime.h>
#include <hip/hip_bf16.h>
#include <math.h>

#define H 128
#define R 32
#define NATOMS 2048
#define NEDGES 32768
#define NH (NATOMS * H)          // 262144 (n,h) pairs
#define NP 1152                  // 9*H: node-plane row stride (interleaved [n][9][H])
#define CUTOFF_F 4.5f
#define PI_OVER_CUTOFF 0.6981317007977318f

typedef __bf16 bf16x8 __attribute__((ext_vector_type(8)));
typedef float f32x4 __attribute__((ext_vector_type(4)));
typedef short short8 __attribute__((ext_vector_type(8)));
typedef unsigned short u16x4 __attribute__((ext_vector_type(4)));

// lgkm-only barrier: LDS visible, global loads stay in flight across it.
#define BAR_LGKM() do { \
    asm volatile("s_waitcnt lgkmcnt(0)" ::: "memory"); \
    __builtin_amdgcn_s_barrier(); \
    asm volatile("" ::: "memory"); \
} while (0)

// ---------------------------------------------------------------------------
// v_rcp_f32 (1 instr, ~1ulp) instead of IEEE divide (~10 instr) — bf16-safe.
__device__ __forceinline__ float rcp_f(float x) {
    return __builtin_amdgcn_rcpf(x);
}
__device__ __forceinline__ float silu_f(float x) {
    return x * rcp_f(1.f + __expf(-x));
}
__device__ __forceinline__ float b2f(unsigned short u) {
    return __uint_as_float(((unsigned)u) << 16);
}
__device__ __forceinline__ unsigned short f2b(float f) {
    __hip_bfloat16 h = __float2bfloat16(f);
    return __builtin_bit_cast(unsigned short, h);
}

// Build full 3x3 from decomposition [i0, a01, a02, a12, s00, s01, s02, s11, s12]
__device__ __forceinline__ void build_full(const float d[9], float m[9]) {
    float i0 = d[0], a01 = d[1], a02 = d[2], a12 = d[3];
    float s00 = d[4], s01 = d[5], s02 = d[6], s11 = d[7], s12 = d[8];
    float s22 = -(s00 + s11);
    m[0] = i0 + s00;  m[1] = a01 + s01;  m[2] = a02 + s02;
    m[3] = s01 - a01; m[4] = i0 + s11;   m[5] = a12 + s12;
    m[6] = s02 - a02; m[7] = s12 - a12;  m[8] = i0 + s22;
}

// ---------------------------------------------------------------------------
// One-shot cast of all fp32 params to bf16 (VECTORIZED float4 -> ushort4)
// + CSR cnt zeroing + node prep.
#define C0 (NEDGES * R)          // edge_attr
#define C1 (2 * H * R)           // Ws1
#define C2 (2 * 2 * H * H)       // Ws2
#define C3 (2 * 3 * H * 2 * H)   // Ws3
#define C4 (2 * 6 * H * H)       // Wt
#define CV ((C0 + C1 + C2 + C3 + C4) / 4)   // 4-elem packs (all ranges 4-divisible)
#define C5 2048                  // cnt zero
#define CAST_TOTAL (CV + C5 + NH)

__device__ __forceinline__ void cast4(const float* __restrict__ src,
                                      unsigned short* __restrict__ dst, int j) {
    float4 v = *(const float4*)(src + j);
    u16x4 o;
    o[0] = f2b(v.x); o[1] = f2b(v.y); o[2] = f2b(v.z); o[3] = f2b(v.w);
    *(u16x4*)(dst + j) = o;
}

__global__ __launch_bounds__(256) void k_cast_all(
        const float* __restrict__ ea, const float* __restrict__ w1,
        const float* __restrict__ w2, const float* __restrict__ w3,
        const float* __restrict__ wt,
        __hip_bfloat16* __restrict__ oea, __hip_bfloat16* __restrict__ ow1,
        __hip_bfloat16* __restrict__ ow2, __hip_bfloat16* __restrict__ ow3,
        __hip_bfloat16* __restrict__ owt, int* __restrict__ cnt,
        const float* __restrict__ X, float* __restrict__ Xn,
        __hip_bfloat16* __restrict__ Db) {
    int i = blockIdx.x * 256 + threadIdx.x;
    if (i < CV) {
        int j = i * 4;
        if (j < C0) { cast4(ea, (unsigned short*)oea, j); return; }
        j -= C0;
        if (j < C1) { cast4(w1, (unsigned short*)ow1, j); return; }
        j -= C1;
        if (j < C2) { cast4(w2, (unsigned short*)ow2, j); return; }
        j -= C2;
        if (j < C3) { cast4(w3, (unsigned short*)ow3, j); return; }
        j -= C3;
        cast4(wt, (unsigned short*)owt, j);
        return;
    }
    i -= CV;
    if (i < C5) { cnt[i] = 0; return; }
    i -= C5;
    if (i < NH) {
        const float* x = X + (size_t)i * 9;
        float v[9];
        float ss = 0.f;
#pragma unroll
        for (int j = 0; j < 9; j++) { v[j] = x[j]; ss += v[j] * v[j]; }
        float inv = rcp_f(ss + 1.f);
#pragma unroll
        for (int j = 0; j < 9; j++) { v[j] *= inv; Xn[(size_t)i * 9 + j] = v[j]; }
        float i0 = (v[0] + v[4] + v[8]) * (1.f / 3.f);
        unsigned short* D = (unsigned short*)Db + (size_t)(i >> 7) * NP + (i & 127);
        D[0 * H] = f2b(i0);
        D[1 * H] = f2b(0.5f * (v[1] - v[3]));
        D[2 * H] = f2b(0.5f * (v[2] - v[6]));
        D[3 * H] = f2b(0.5f * (v[5] - v[7]));
        D[4 * H] = f2b(v[0] - i0);
        D[5 * H] = f2b(0.5f * (v[1] + v[3]));
        D[6 * H] = f2b(0.5f * (v[2] + v[6]));
        D[7 * H] = f2b(v[4] - i0);
        D[8 * H] = f2b(0.5f * (v[5] + v[7]));
    }
}

// ---------------------------------------------------------------------------
// bf16 MFMA 128x64 tile-GEMM core for the channel mix (K=128), strided A.
// GUARDED variant: only threads with `active` do work; barriers are
// unconditional so it can run inside a 512-thread block with 256 workers.
struct TGm {
    static constexpr int BKm = 64;
    static constexpr int RB  = 128;        // row bytes per K-step
    static constexpr int SWZ = 7;
    static constexpr int NIT = 2;
    static constexpr int ABYTES = 128 * RB;
    static constexpr int BBYTES = 64 * RB;
    static constexpr int AISS = ABYTES / 4096;
    static constexpr int BISS = BBYTES / 4096;
    static constexpr int LDSB = ABYTES + BBYTES;
};

__device__ __forceinline__ void tile_gemm_mix_g(
        const __hip_bfloat16* __restrict__ A, int strideA,
        const __hip_bfloat16* __restrict__ W,
        int m0, int n0, char* lds, f32x4 acc[4][2], bool active) {
    using T = TGm;
    const int t = threadIdx.x;
    const int lane = t & 63;
    const int w = t >> 6;

    auto stage = [&](int b, int it) {
        const int k0 = it * T::BKm;
        char* As = lds + b * T::LDSB;
        char* Bs = As + T::ABYTES;
#pragma unroll
        for (int i = 0; i < T::AISS; i++) {
            int base = (w * T::AISS + i) * 1024;
            int lin = base + lane * 16;
            int row = lin / T::RB;
            int slot = (lin % T::RB) >> 4;
            int sl = slot ^ (row & T::SWZ);
            const char* src = (const char*)(A + (size_t)(m0 + row) * strideA + k0) + sl * 16;
            __builtin_amdgcn_global_load_lds(
                (const __attribute__((address_space(1))) void*)src,
                (__attribute__((address_space(3))) void*)(As + base), 16, 0, 0);
        }
#pragma unroll
        for (int i = 0; i < T::BISS; i++) {
            int base = (w * T::BISS + i) * 1024;
            int lin = base + lane * 16;
            int row = lin / T::RB;
            int slot = (lin % T::RB) >> 4;
            int sl = slot ^ (row & T::SWZ);
            const char* src = (const char*)(W + (size_t)(n0 + row) * H + k0) + sl * 16;
            __builtin_amdgcn_global_load_lds(
                (const __attribute__((address_space(1))) void*)src,
                (__attribute__((address_space(3))) void*)(Bs + base), 16, 0, 0);
        }
    };

    auto compute = [&](int b) {
        const char* As = lds + b * T::LDSB;
        const char* Bs = As + T::ABYTES;
        const int wm = (w & 1) * 64;
        const int wn = (w >> 1) * 32;
        const int rA = wm + (lane & 15);
        const int rB = wn + (lane & 15);
        const int c = lane >> 4;
#pragma unroll
        for (int kk = 0; kk < T::BKm / 32; kk++) {
            bf16x8 av[4], bv[2];
#pragma unroll
            for (int mf = 0; mf < 4; mf++) {
                int row = rA + mf * 16;
                int sp = (kk * 4 + c) ^ (row & T::SWZ);
                av[mf] = __builtin_bit_cast(bf16x8,
                    *(const short8*)(As + row * T::RB + sp * 16));
            }
#pragma unroll
            for (int nf = 0; nf < 2; nf++) {
                int row = rB + nf * 16;
                int sp = (kk * 4 + c) ^ (row & T::SWZ);
                bv[nf] = __builtin_bit_cast(bf16x8,
                    *(const short8*)(Bs + row * T::RB + sp * 16));
            }
#pragma unroll
            for (int mf = 0; mf < 4; mf++)
#pragma unroll
                for (int nf = 0; nf < 2; nf++)
                    acc[mf][nf] = __builtin_amdgcn_mfma_f32_16x16x32_bf16(
                        av[mf], bv[nf], acc[mf][nf], 0, 0, 0);
        }
    };

    if (active) stage(0, 0);
    asm volatile("s_waitcnt vmcnt(0)" ::: "memory");
    __syncthreads();
    for (int it = 0; it < T::NIT; it++) {
        int b = it & 1;
        if (active && it + 1 < T::NIT) stage(b ^ 1, it + 1);
        if (active) compute(b);
        asm volatile("s_waitcnt vmcnt(0)" ::: "memory");
        __syncthreads();
    }
}

// Standalone channel-mix (256 threads): 9 planes [n][9][H] @ Wt-part.
__global__ __launch_bounds__(256) void k_mix(
        const __hip_bfloat16* __restrict__ Db, const __hip_bfloat16* __restrict__ Wtb,
        __hip_bfloat16* __restrict__ Outp, int partOff) {
    __shared__ char lds[2 * TGm::LDSB];
    int c = blockIdx.z;
    int part = (c == 0) ? 0 : ((c < 4) ? 1 : 2);
    const __hip_bfloat16* A = Db + (size_t)c * H;
    const __hip_bfloat16* W = Wtb + (size_t)(partOff + part) * H * H;
    unsigned short* Out = (unsigned short*)Outp + (size_t)c * H;
    const int lane = threadIdx.x & 63;
    const int w = threadIdx.x >> 6;
    const int wm = (w & 1) * 64, wn = (w >> 1) * 32;
    const int m0 = blockIdx.x * 128, n0 = blockIdx.y * 64;
    f32x4 acc[4][2] = {};
    tile_gemm_mix_g(A, NP, W, m0, n0, lds, acc, true);
#pragma unroll
    for (int mf = 0; mf < 4; mf++)
#pragma unroll
        for (int r = 0; r < 4; r++) {
            int row = m0 + wm + mf * 16 + (lane >> 4) * 4 + r;
#pragma unroll
            for (int nf = 0; nf < 2; nf++) {
                int col = n0 + wn + nf * 16 + (lane & 15);
                Out[(size_t)row * NP + col] = f2b(acc[mf][nf][r]);
            }
        }
}

// ---------------------------------------------------------------------------
// FAT kernel: blocks [0, MIXBLOCKS) do the layer-0 Y channel-mix (256 active
// threads of 512); blocks [MIXBLOCKS, +1024) do the fused 3-stage edge MLP
// for both layers. The two roles are independent (both consume only
// k_cast_all outputs), so the mix hides in the MLP's idle issue slots.
#define ETILE 64
#define PAD0 40     // sEA row stride (elements)
#define PAD1 136    // act1 row stride
#define PAD2 264    // act2 row stride
#define SA2_B (ETILE * PAD2 * 2)   // 33792 bytes: act2 region (base)
#define SA1_B (ETILE * PAD1 * 2)   // 17408 bytes: act1 (at base, inside act2)
#define SEA_OFF SA1_B              // sEA right after act1 (inside act2 region)
#define MIXBLOCKS 288              // 16 m-tiles x 2 n-tiles x 9 planes
#define FAT_LDS (2 * TGm::LDSB + 256)   // 49408: union of mix(48K) and mlp(34K+ew)

__global__ __launch_bounds__(512, 3) void k_fat(
        const __hip_bfloat16* __restrict__ eaB,
        const __hip_bfloat16* __restrict__ W1b, const __hip_bfloat16* __restrict__ W2b,
        const __hip_bfloat16* __restrict__ W3b,
        const float* __restrict__ bs1, const float* __restrict__ bs2,
        const float* __restrict__ bs3, const float* __restrict__ ew,
        __hip_bfloat16* __restrict__ ea3g,
        const __hip_bfloat16* __restrict__ Db, const __hip_bfloat16* __restrict__ Wtb,
        __hip_bfloat16* __restrict__ Yb) {
    __shared__ char smem[FAT_LDS];
    int bid = blockIdx.x;

    if (bid < MIXBLOCKS) {
        // ---- mix role: layer-0 Y = chan_mix(Db) ----
        int c = bid / 32;
        int rem = bid & 31;
        int m0 = (rem & 15) * 128;
        int n0 = (rem >> 4) * 64;
        int part = (c == 0) ? 0 : ((c < 4) ? 1 : 2);
        const __hip_bfloat16* A = Db + (size_t)c * H;
        const __hip_bfloat16* W = Wtb + (size_t)part * H * H;
        unsigned short* Out = (unsigned short*)Yb + (size_t)c * H;
        bool active = threadIdx.x < 256;
        f32x4 acc[4][2] = {};
        tile_gemm_mix_g(A, NP, W, m0, n0, smem, acc, active);
        if (active) {
            const int lane = threadIdx.x & 63;
            const int w = threadIdx.x >> 6;
            const int wm = (w & 1) * 64, wn = (w >> 1) * 32;
#pragma unroll
            for (int mf = 0; mf < 4; mf++)
#pragma unroll
                for (int r = 0; r < 4; r++) {
                    int row = m0 + wm + mf * 16 + (lane >> 4) * 4 + r;
#pragma unroll
                    for (int nf = 0; nf < 2; nf++) {
                        int col = n0 + wn + nf * 16 + (lane & 15);
                        Out[(size_t)row * NP + col] = f2b(acc[mf][nf][r]);
                    }
                }
        }
        return;
    }
    bid -= MIXBLOCKS;

    // ---- mlp role ----
    const int l = bid >> 9;
    const unsigned short* W1 = (const unsigned short*)W1b + (size_t)l * (H * R);
    const unsigned short* W2 = (const unsigned short*)W2b + (size_t)l * (2 * H * H);
    const unsigned short* W3 = (const unsigned short*)W3b + (size_t)l * (3 * H * 2 * H);
    const float* b1 = bs1 + (size_t)l * H;
    const float* b2 = bs2 + (size_t)l * 2 * H;
    const float* b3 = bs3 + (size_t)l * 3 * H;
    unsigned short* outp = (unsigned short*)ea3g + (size_t)l * NEDGES * 384;
    const int e0 = (bid & 511) * ETILE;

    unsigned short* sA2 = (unsigned short*)smem;               // [64][PAD2]
    unsigned short* sA1 = (unsigned short*)smem;               // [64][PAD1] at base
    unsigned short* sEA = (unsigned short*)(smem + SEA_OFF);   // [64][PAD0]
    float* sEW = (float*)(smem + SA2_B);                       // ew cache

    const int t = threadIdx.x;
    const int lane = t & 63;
    const int w = t >> 6;        // 0..7
    const int q = lane >> 4;     // k-chunk index (0..3)
    const int li = lane & 15;

    const int cbase1 = w * 16;
    const int cbase2 = w * 32;
    const int cbase3 = w * 48;

    // Early global issues (independent of LDS): W1 fragment + bias1.
    bf16x8 av1 = __builtin_bit_cast(bf16x8,
        *(const short8*)(W1 + (size_t)(cbase1 + li) * R + q * 8));
    f32x4 bb1 = *(const f32x4*)&b1[cbase1 + q * 4];

    // stage edge_attr tile [64][32] + ew tile
    {
        if (t < 256) {
            int row = t >> 2, c8 = t & 3;
            *(uint4*)(sEA + row * PAD0 + c8 * 8) =
                *(const uint4*)((const unsigned short*)eaB + (size_t)(e0 + row) * R + c8 * 8);
        }
        if (t < ETILE) sEW[t] = ew[e0 + t];
    }
    BAR_LGKM();                                       // (1) sEA/sEW visible

    // ---- GEMM1: W1[128,32] @ ea^T -> act1^T ----
    f32x4 acc1[4] = {};
#pragma unroll
    for (int ef = 0; ef < 4; ef++) {
        bf16x8 bv = __builtin_bit_cast(bf16x8,
            *(const short8*)(sEA + (ef * 16 + li) * PAD0 + q * 8));
        acc1[ef] = __builtin_amdgcn_mfma_f32_16x16x32_bf16(av1, bv, acc1[ef], 0, 0, 0);
    }

    // Issue ALL GEMM2 weights now — they fly across GEMM1 epilogue + barrier.
    bf16x8 a2[4][2];
#pragma unroll
    for (int ks = 0; ks < 4; ks++)
#pragma unroll
        for (int mf = 0; mf < 2; mf++)
            a2[ks][mf] = __builtin_bit_cast(bf16x8,
                *(const short8*)(W2 + (size_t)(cbase2 + mf * 16 + li) * H
                                 + ks * 32 + q * 8));
    f32x4 bb2[2];
#pragma unroll
    for (int mf = 0; mf < 2; mf++)
        bb2[mf] = *(const f32x4*)&b2[cbase2 + mf * 16 + q * 4];

    // GEMM1 epilogue (writes act1 region [0..SA1_B), disjoint from sEA)
#pragma unroll
    for (int ef = 0; ef < 4; ef++) {
        u16x4 o;
#pragma unroll
        for (int r = 0; r < 4; r++) o[r] = f2b(silu_f(acc1[ef][r] + bb1[r]));
        *(u16x4*)(sA1 + (ef * 16 + li) * PAD1 + cbase1 + q * 4) = o;
    }
    BAR_LGKM();                                       // (2) act1 visible

    // ---- GEMM2: W2[256,128] @ act1^T -> act2^T (weights all in regs) ----
    f32x4 acc2[2][4] = {};
#pragma unroll
    for (int ks = 0; ks < 4; ks++) {
        bf16x8 bv[4];
#pragma unroll
        for (int ef = 0; ef < 4; ef++)
            bv[ef] = __builtin_bit_cast(bf16x8,
                *(const short8*)(sA1 + (ef * 16 + li) * PAD1 + ks * 32 + q * 8));
#pragma unroll
        for (int mf = 0; mf < 2; mf++)
#pragma unroll
            for (int ef = 0; ef < 4; ef++)
                acc2[mf][ef] = __builtin_amdgcn_mfma_f32_16x16x32_bf16(
                    a2[ks][mf], bv[ef], acc2[mf][ef], 0, 0, 0);
    }

    // Issue GEMM3's first 3 k-slice weights — fly across epilogue + 2 barriers.
    bf16x8 a3[3][3];   // [ks%3][mf]
#pragma unroll
    for (int pk = 0; pk < 3; pk++)
#pragma unroll
        for (int mf = 0; mf < 3; mf++)
            a3[pk][mf] = __builtin_bit_cast(bf16x8,
                *(const short8*)(W3 + (size_t)(cbase3 + mf * 16 + li) * (2 * H)
                                 + pk * 32 + q * 8));

    BAR_LGKM();   // (3) all act1/sEA reads done; safe to overwrite with act2
#pragma unroll
    for (int mf = 0; mf < 2; mf++)
#pragma unroll
        for (int ef = 0; ef < 4; ef++) {
            u16x4 o;
#pragma unroll
            for (int r = 0; r < 4; r++)
                o[r] = f2b(silu_f(acc2[mf][ef][r] + bb2[mf][r]));
            *(u16x4*)(sA2 + (ef * 16 + li) * PAD2 + cbase2 + mf * 16 + q * 4) = o;
        }
    BAR_LGKM();                                       // (4) act2 visible

    // ---- GEMM3: W3[384,256] @ act2^T, 3-deep rotating weight prefetch ----
    f32x4 acc3[3][4] = {};
#pragma unroll
    for (int ks = 0; ks < 8; ks++) {
        const int slot = ks % 3;
        bf16x8 bv[4];
#pragma unroll
        for (int ef = 0; ef < 4; ef++)
            bv[ef] = __builtin_bit_cast(bf16x8,
                *(const short8*)(sA2 + (ef * 16 + li) * PAD2 + ks * 32 + q * 8));
#pragma unroll
        for (int mf = 0; mf < 3; mf++)
#pragma unroll
            for (int ef = 0; ef < 4; ef++)
                acc3[mf][ef] = __builtin_amdgcn_mfma_f32_16x16x32_bf16(
                    a3[slot][mf], bv[ef], acc3[mf][ef], 0, 0, 0);
        if (ks + 3 < 8) {   // reload this slot for iteration ks+3
#pragma unroll
            for (int mf = 0; mf < 3; mf++)
                a3[slot][mf] = __builtin_bit_cast(bf16x8,
                    *(const short8*)(W3 + (size_t)(cbase3 + mf * 16 + li) * (2 * H)
                                     + (ks + 3) * 32 + q * 8));
        }
    }
    f32x4 bb3[3];
#pragma unroll
    for (int mf = 0; mf < 3; mf++)
        bb3[mf] = *(const f32x4*)&b3[cbase3 + mf * 16 + q * 4];
#pragma unroll
    for (int ef = 0; ef < 4; ef++) {
        int edge = ef * 16 + li;
        float wv = sEW[edge];
        float cs = (wv < CUTOFF_F) ? 0.5f * (__cosf(wv * PI_OVER_CUTOFF) + 1.f) : 0.f;
#pragma unroll
        for (int mf = 0; mf < 3; mf++) {
            u16x4 o;
#pragma unroll
            for (int r = 0; r < 4; r++)
                o[r] = f2b(silu_f(acc3[mf][ef][r] + bb3[mf][r]) * cs);
            *(u16x4*)(outp + (size_t)(e0 + edge) * 384 + cbase3 + mf * 16 + q * 4) = o;
        }
    }
}

// ---------------------------------------------------------------------------
// CSR build (once; edge_index is static across layers)
__global__ __launch_bounds__(256) void k_hist(
        const int* __restrict__ eidx, int* __restrict__ cnt) {
    int e = blockIdx.x * 256 + threadIdx.x;
    if (e < NEDGES) atomicAdd(&cnt[eidx[e]], 1);
}

__global__ __launch_bounds__(256) void k_scan(
        const int* __restrict__ cnt, int* __restrict__ rowstart,
        int* __restrict__ cursor) {
    __shared__ int partial[256];
    int t = threadIdx.x;
    int loc[8];
    int run = 0;
#pragma unroll
    for (int j = 0; j < 8; j++) {
        int v = cnt[t * 8 + j];
        loc[j] = run; run += v;
    }
    partial[t] = run;
    __syncthreads();
    if (t == 0) {
        int acc = 0;
        for (int i = 0; i < 256; i++) { int v = partial[i]; partial[i] = acc; acc += v; }
        rowstart[2048] = acc;
    }
    __syncthreads();
    int base = partial[t];
#pragma unroll
    for (int j = 0; j < 8; j++) {
        rowstart[t * 8 + j] = base + loc[j];
        cursor[t * 8 + j] = base + loc[j];
    }
}

__global__ __launch_bounds__(256) void k_fill(
        const int* __restrict__ eidx, int* __restrict__ cursor,
        int* __restrict__ elist) {
    int e = blockIdx.x * 256 + threadIdx.x;
    if (e >= NEDGES) return;
    int src = eidx[e];
    int pos = atomicAdd(&cursor[src], 1);
    elist[pos] = e;
}

// ---------------------------------------------------------------------------
// Gather + fused abnorm: NH threads; adjacent lane pairs split a node's
// edge list; software-pipelined edge loop (prefetch next elist/eidx).
__global__ __launch_bounds__(256) void k_gather_ab(
        const __hip_bfloat16* __restrict__ ea /* [E][384], col=h*3+comp */,
        const int* __restrict__ eidx,
        const int* __restrict__ rowstart, const int* __restrict__ elist,
        const __hip_bfloat16* __restrict__ Yb, const float* __restrict__ q,
        __hip_bfloat16* __restrict__ Tb) {
    int gid = blockIdx.x * 256 + threadIdx.x;   // NH threads
    int n = gid >> 7;
    int t7 = gid & 127;
    int hp = t7 >> 1;          // h-pair index 0..63
    int half = t7 & 1;         // which half of the edge list / which column
    int h0 = hp << 1;
    int beg = rowstart[n], end = rowstart[n + 1];
    const unsigned short* Y = (const unsigned short*)Yb;

    // hoisted loads that overlap the edge loop
    float scale = 1.f + 0.1f * q[n];
    int hcol = h0 + half;
    const unsigned short* ypn = Y + (size_t)n * NP + hcol;
    float yd[9];
#pragma unroll
    for (int c = 0; c < 9; c++) yd[c] = b2f(ypn[(size_t)c * H]);

    float acc[9][2];
#pragma unroll
    for (int c = 0; c < 9; c++) { acc[c][0] = 0.f; acc[c][1] = 0.f; }

    int idx = beg + half;
    int e = 0, dst = 0;
    if (idx < end) { e = elist[idx]; dst = eidx[NEDGES + e]; }
    while (idx < end) {
        int nidx = idx + 2;
        int ne = e, ndst = dst;
        if (nidx < end) { ne = elist[nidx]; ndst = eidx[NEDGES + ne]; }
        const unsigned short* eap = (const unsigned short*)ea + (size_t)e * 384 + h0 * 3;
        unsigned u0 = *(const unsigned*)(eap);
        unsigned u1 = *(const unsigned*)(eap + 2);
        unsigned u2 = *(const unsigned*)(eap + 4);
        float w0a = b2f(u0 & 0xffff), w1a = b2f(u0 >> 16);
        float w2a = b2f(u1 & 0xffff), w0b = b2f(u1 >> 16);
        float w1b = b2f(u2 & 0xffff), w2b = b2f(u2 >> 16);
        const unsigned short* yp = Y + (size_t)dst * NP + h0;
        ushort2 y;
        y = *(const ushort2*)(yp + 0 * H); acc[0][0] += w0a * b2f(y.x); acc[0][1] += w0b * b2f(y.y);
        y = *(const ushort2*)(yp + 1 * H); acc[1][0] += w1a * b2f(y.x); acc[1][1] += w1b * b2f(y.y);
        y = *(const ushort2*)(yp + 2 * H); acc[2][0] += w1a * b2f(y.x); acc[2][1] += w1b * b2f(y.y);
        y = *(const ushort2*)(yp + 3 * H); acc[3][0] += w1a * b2f(y.x); acc[3][1] += w1b * b2f(y.y);
#pragma unroll
        for (int c = 4; c < 9; c++) {
            y = *(const ushort2*)(yp + c * H);
            acc[c][0] += w2a * b2f(y.x); acc[c][1] += w2b * b2f(y.y);
        }
        idx = nidx; e = ne; dst = ndst;
    }
    // combine the two halves (lanes differ only in bit 0)
#pragma unroll
    for (int c = 0; c < 9; c++) {
        acc[c][0] += __shfl_xor(acc[c][0], 1);
        acc[c][1] += __shfl_xor(acc[c][1], 1);
    }
    // fused abnorm: this lane handles column h0+half
    float md[9];
#pragma unroll
    for (int c = 0; c < 9; c++) md[c] = acc[c][half];
    float m[9], yf[9];
    build_full(md, m);
    build_full(yd, yf);
    float ab[9];
#pragma unroll
    for (int ii = 0; ii < 3; ii++)
#pragma unroll
        for (int jj = 0; jj < 3; jj++) {
            float s = 0.f;
#pragma unroll
            for (int kk = 0; kk < 3; kk++)
                s += m[ii * 3 + kk] * yf[kk * 3 + jj] + yf[ii * 3 + kk] * m[kk * 3 + jj];
            ab[ii * 3 + jj] = s;
        }
    float nrm = 0.f;
#pragma unroll
    for (int j = 0; j < 9; j++) { ab[j] *= scale; nrm += ab[j] * ab[j]; }
    float inv = rcp_f(nrm + 1.f);
    float tr3 = (ab[0] + ab[4] + ab[8]) * (1.f / 3.f);
    unsigned short* T = (unsigned short*)Tb + (size_t)n * NP + hcol;
    T[0 * H] = f2b(tr3 * inv);
    T[1 * H] = f2b(0.5f * (ab[1] - ab[3]) * inv);
    T[2 * H] = f2b(0.5f * (ab[2] - ab[6]) * inv);
    T[3 * H] = f2b(0.5f * (ab[5] - ab[7]) * inv);
    T[4 * H] = f2b((ab[0] - tr3) * inv);
    T[5 * H] = f2b(0.5f * (ab[1] + ab[3]) * inv);
    T[6 * H] = f2b(0.5f * (ab[2] + ab[6]) * inv);
    T[7 * H] = f2b((ab[4] - tr3) * inv);
    T[8 * H] = f2b(0.5f * (ab[5] + ab[7]) * inv);
}

// ---------------------------------------------------------------------------
// Final: Xout = Xn + dX + (1+0.1q)*dX@dX.  dX interleaved bf16 [n][9][H].
// PREP: also normalize+decompose Xout into Xn (fp32) and Db (bf16) for next layer.
template <bool PREP>
__global__ __launch_bounds__(256) void k_final(
        const __hip_bfloat16* __restrict__ dXb, const float* __restrict__ Xn,
        const float* __restrict__ q, float* __restrict__ Xout,
        float* __restrict__ XnW, __hip_bfloat16* __restrict__ Db) {
    int i = blockIdx.x * 256 + threadIdx.x;
    if (i >= NH) return;
    const unsigned short* dX = (const unsigned short*)dXb + (size_t)(i >> 7) * NP + (i & 127);
    float dd[9];
#pragma unroll
    for (int c = 0; c < 9; c++) dd[c] = b2f(dX[(size_t)c * H]);
    float dx[9];
    build_full(dd, dx);
    float scale = 1.f + 0.1f * q[i >> 7];
    float out[9];
#pragma unroll
    for (int ii = 0; ii < 3; ii++)
#pragma unroll
        for (int jj = 0; jj < 3; jj++) {
            float s = 0.f;
#pragma unroll
            for (int kk = 0; kk < 3; kk++)
                s += dx[ii * 3 + kk] * dx[kk * 3 + jj];
            out[ii * 3 + jj] = Xn[(size_t)i * 9 + ii * 3 + jj] + dx[ii * 3 + jj] + scale * s;
        }
#pragma unroll
    for (int j = 0; j < 9; j++) Xout[(size_t)i * 9 + j] = out[j];
    if (PREP) {
        float ss = 0.f;
#pragma unroll
        for (int j = 0; j < 9; j++) ss += out[j] * out[j];
        float inv = rcp_f(ss + 1.f);
        float v[9];
#pragma unroll
        for (int j = 0; j < 9; j++) { v[j] = out[j] * inv; XnW[(size_t)i * 9 + j] = v[j]; }
        float i0 = (v[0] + v[4] + v[8]) * (1.f / 3.f);
        unsigned short* D = (unsigned short*)Db + (size_t)(i >> 7) * NP + (i & 127);
        D[0 * H] = f2b(i0);
        D[1 * H] = f2b(0.5f * (v[1] - v[3]));
        D[2 * H] = f2b(0.5f * (v[2] - v[6]));
        D[3 * H] = f2b(0.5f * (v[5] - v[7]));
        D[4 * H] = f2b(v[0] - i0);
        D[5 * H] = f2b(0.5f * (v[1] + v[3]));
        D[6 * H] = f2b(0.5f * (v[2] + v[6]));
        D[7 * H] = f2b(v[4] - i0);
        D[8 * H] = f2b(0.5f * (v[5] + v[7]));
    }
}

// ---------------------------------------------------------------------------
extern "C" void kernel_launch(void* const* d_in, const int* in_sizes, int n_in,
                              void* d_out, int out_size, void* d_ws, size_t ws_size,
                              hipStream_t stream) {
    const float* X          = (const float*)d_in[0];
    const float* edge_attr  = (const float*)d_in[1];
    const float* edge_weight= (const float*)d_in[2];
    const float* q          = (const float*)d_in[3];
    const float* Ws1        = (const float*)d_in[4];
    const float* bs1        = (const float*)d_in[5];
    const float* Ws2        = (const float*)d_in[6];
    const float* bs2        = (const float*)d_in[7];
    const float* Ws3        = (const float*)d_in[8];
    const float* bs3        = (const float*)d_in[9];
    const float* Wt         = (const float*)d_in[10];
    const int*   eidx       = (const int*)d_in[11];
    float* Xout = (float*)d_out;

    char* p = (char*)d_ws;
    auto alloc = [&](size_t bytes) -> char* {
        char* r = p; p += (bytes + 255) & ~(size_t)255; return r;
    };
    size_t nodeBytes = (size_t)NH * 9 * sizeof(float);
    float* Xn   = (float*)alloc(nodeBytes);
    __hip_bfloat16* Db = (__hip_bfloat16*)alloc((size_t)NH * 9 * 2);  // D / T planes
    __hip_bfloat16* Yb = (__hip_bfloat16*)alloc((size_t)NH * 9 * 2);  // Y, then dX
    __hip_bfloat16* eaB = (__hip_bfloat16*)alloc((size_t)C0 * 2);
    __hip_bfloat16* W1b = (__hip_bfloat16*)alloc((size_t)C1 * 2);
    __hip_bfloat16* W2b = (__hip_bfloat16*)alloc((size_t)C2 * 2);
    __hip_bfloat16* W3b = (__hip_bfloat16*)alloc((size_t)C3 * 2);
    __hip_bfloat16* Wtb = (__hip_bfloat16*)alloc((size_t)C4 * 2);
    __hip_bfloat16* ea3g = (__hip_bfloat16*)alloc((size_t)2 * NEDGES * 384 * 2);
    int* cnt      = (int*)alloc(2048 * 4);
    int* rowstart = (int*)alloc(2049 * 4);
    int* cursor   = (int*)alloc(2048 * 4);
    int* elist    = (int*)alloc(NEDGES * 4);

    // one-time bf16 casts (vectorized) + cnt zeroing + node prep (fused)
    k_cast_all<<<(CAST_TOTAL + 255) / 256, 256, 0, stream>>>(
        edge_attr, Ws1, Ws2, Ws3, Wt, eaB, W1b, W2b, W3b, Wtb, cnt,
        X, Xn, Db);

    // CSR once (edge_index static across layers)
    k_hist<<<NEDGES / 256, 256, 0, stream>>>(eidx, cnt);
    k_scan<<<1, 256, 0, stream>>>(cnt, rowstart, cursor);
    k_fill<<<NEDGES / 256, 256, 0, stream>>>(eidx, cursor, elist);

    // FAT: layer-0 Y-mix (288 blocks) + edge MLP both layers (1024 blocks)
    k_fat<<<MIXBLOCKS + 1024, 512, 0, stream>>>(
        eaB, W1b, W2b, W3b, bs1, bs2, bs3, edge_weight, ea3g,
        Db, Wtb, Yb);

    for (int l = 0; l < 2; l++) {
        const __hip_bfloat16* Wtl = Wtb + (size_t)l * 6 * H * H;
        const __hip_bfloat16* ea3 = ea3g + (size_t)l * NEDGES * 384;

        if (l == 1) {
            // Y = chan_mix(decomposed Xn) for layer 1
            k_mix<<<dim3(NATOMS / 128, 2, 9), 256, 0, stream>>>(Db, Wtl, Yb, 0);
        }
        // gather + fused abnorm -> Tb (reuses Db)
        k_gather_ab<<<NH / 256, 256, 0, stream>>>(
            ea3, eidx, rowstart, elist, Yb, q, Db);
        // dX = chan_mix(T) -> bf16 interleaved planes (reuses Yb)
        k_mix<<<dim3(NATOMS / 128, 2, 9), 256, 0, stream>>>(Db, Wtl, Yb, 3);
        // final (+ fused node-prep for next layer)
        if (l == 0)
            k_final<true><<<NH / 256, 256, 0, stream>>>(Yb, Xn, q, Xout, Xn, Db);
        else
            k_final<false><<<NH / 256, 256, 0, stream>>>(Yb, Xn, q, Xout, nullptr, nullptr);
    }
}